// Round 10
// baseline (1388.661 us; speedup 1.0000x reference)
//
#include <hip/hip_runtime.h>
#include <cmath>

#define NB 4
#define NN 8192
#define CH 32
#define GRID 512

typedef short short8 __attribute__((ext_vector_type(8)));
typedef float floatx4 __attribute__((ext_vector_type(4)));
typedef unsigned short ushort_t;

// ---------- helpers ----------
__device__ __forceinline__ unsigned short f2b(float f){
  unsigned u = __float_as_uint(f);
  u = u + 0x7FFFu + ((u >> 16) & 1u);   // RNE
  return (unsigned short)(u >> 16);
}
__device__ __forceinline__ float b2f(unsigned short h){
  return __uint_as_float(((unsigned)h) << 16);
}
__device__ __forceinline__ float gelu_f(float v){
  return 0.5f * v * (1.0f + erff(v * 0.70710678118654752440f));
}
__device__ __forceinline__ int repk(int t){
  int j = t / 24, i = t - j * 24;
  if(j == 0)  return (i <= 12) ? i : -1;
  if(j <= 11) return 13 + (j - 1) * 24 + i;
  return (i == 12) ? 277 + (j - 12) : -1;
}
__device__ __forceinline__ int partner(int t){
  int j = t / 24, i = t - j * 24;
  return ((23 - j) % 23) * 24 + ((24 - i) % 24);
}
__device__ __forceinline__ int repT(int k){
  if(k < 13) return k;
  if(k < 277){ int m = k - 13; return (m / 24 + 1) * 24 + (m % 24); }
  return (k - 277 + 12) * 24 + 12;
}

// ---------- hand-rolled grid barrier (device-scope, graph-capture-safe) ----------
// Generation-based. Arrive: fetch_add(cnt, ACQ_REL). Last arriver resets cnt
// (RELAXED, ordered before gen release) then bumps gen (RELEASE). Waiters
// acquire-load gen with s_sleep backoff. __threadfence() before/after as
// belt-and-braces for cross-XCD L2 writeback/invalidate (G16 mitigation).
__device__ __forceinline__ void gbar(unsigned* cnt, unsigned* gen){
  __syncthreads();
  if(threadIdx.x == 0){
    unsigned g = __hip_atomic_load(gen, __ATOMIC_RELAXED, __HIP_MEMORY_SCOPE_AGENT);
    __threadfence();
    unsigned a = __hip_atomic_fetch_add(cnt, 1u, __ATOMIC_ACQ_REL, __HIP_MEMORY_SCOPE_AGENT);
    if(a == (unsigned)GRID - 1u){
      __hip_atomic_store(cnt, 0u, __ATOMIC_RELAXED, __HIP_MEMORY_SCOPE_AGENT);
      __hip_atomic_fetch_add(gen, 1u, __ATOMIC_RELEASE, __HIP_MEMORY_SCOPE_AGENT);
    } else {
      while(__hip_atomic_load(gen, __ATOMIC_ACQUIRE, __HIP_MEMORY_SCOPE_AGENT) == g)
        __builtin_amdgcn_s_sleep(8);
    }
    __threadfence();
  }
  __syncthreads();
}

// ---------- workspace offsets ----------
static constexpr size_t OFF_PMM = 0;
static constexpr size_t OFF_WT  = 4096;
static constexpr size_t OFF_AF  = OFF_WT  + 9437184;
static constexpr size_t OFF_VTF = OFF_AF  + 37748736;
static constexpr size_t OFF_HB0 = OFF_VTF + 37748736;
static constexpr size_t OFF_HB1 = OFF_HB0 + 2097152;
static constexpr size_t OFF_HC0 = OFF_HB1 + 2097152;
static constexpr size_t OFF_HC1 = OFF_HC0 + 2097152;
static constexpr size_t OFF_HL0 = OFF_HC1 + 2097152;
static constexpr size_t OFF_HL1 = OFF_HL0 + 2097152;
static constexpr size_t OFF_XP  = OFF_HL1 + 2097152;
static constexpr size_t OFF_GHF = OFF_XP  + 4718592;
static constexpr size_t OFF_GLO = OFF_GHF + 147456;
static constexpr size_t OFF_WB  = OFF_GLO + 147456;
static constexpr size_t OFF_WA  = OFF_WB  + 16384;
static constexpr size_t OFF_BAR = OFF_WA  + 16384;

struct MArgs {
  const float *x, *fc0w, *fc0b, *spec, *convw, *convb, *fc1w, *fc1b, *fc2w, *fc2b;
  float* out;
  char* ws;
};

// ================= persistent mega-kernel, hand barrier =================
// 512 blocks x 256 thr, launch_bounds(256,2): LDS 37.4KB -> >=2 blocks/CU
// guaranteed -> all 512 co-resident (no deadlock). Phase bodies are VERBATIM
// the R9-proven kernels (absmax bit-exact), wrapped in grid-stride loops.
__global__ __launch_bounds__(256, 2) void k_mega(MArgs A)
{
  __shared__ alignas(16) char SMEM[37392];
  const int tid = threadIdx.x;
  const int B   = blockIdx.x;

  float4*   pmm  = (float4*)(A.ws + OFF_PMM);
  float2*   wt   = (float2*)(A.ws + OFF_WT);
  ushort_t* AF   = (ushort_t*)(A.ws + OFF_AF);
  ushort_t* VTF  = (ushort_t*)(A.ws + OFF_VTF);
  ushort_t* hbB0 = (ushort_t*)(A.ws + OFF_HB0);
  ushort_t* hbB1 = (ushort_t*)(A.ws + OFF_HB1);
  ushort_t* hcH0 = (ushort_t*)(A.ws + OFF_HC0);
  ushort_t* hcH1 = (ushort_t*)(A.ws + OFF_HC1);
  ushort_t* hcL0 = (ushort_t*)(A.ws + OFF_HL0);
  ushort_t* hcL1 = (ushort_t*)(A.ws + OFF_HL1);
  float*    xp   = (float*)(A.ws + OFF_XP);
  ushort_t* ghif = (ushort_t*)(A.ws + OFF_GHF);
  ushort_t* glof = (ushort_t*)(A.ws + OFF_GLO);
  ushort_t* WB   = (ushort_t*)(A.ws + OFF_WB);
  ushort_t* WA   = (ushort_t*)(A.ws + OFF_WA);
  unsigned* bcnt = (unsigned*)(A.ws + OFF_BAR);
  unsigned* bgen = bcnt + 1;

  //======== phase 0: minmax partials + spec reorder + WB/WA ========
  if(B < 128){
    float4* wp = (float4*)SMEM;
    int g = B * 256 + tid;
    float a = A.x[(size_t)g * 2], b = A.x[(size_t)g * 2 + 1];
    float mn0 = a, mx0 = a, mn1 = b, mx1 = b;
    for(int off = 32; off > 0; off >>= 1){
      mn0 = fminf(mn0, __shfl_down(mn0, off));
      mx0 = fmaxf(mx0, __shfl_down(mx0, off));
      mn1 = fminf(mn1, __shfl_down(mn1, off));
      mx1 = fmaxf(mx1, __shfl_down(mx1, off));
    }
    if((tid & 63) == 0) wp[tid >> 6] = make_float4(mn0, mn1, mx0, mx1);
    __syncthreads();
    if(tid == 0){
      float4 r = wp[0];
      for(int i2 = 1; i2 < 4; ++i2){
        float4 v2 = wp[i2];
        r.x = fminf(r.x, v2.x); r.y = fminf(r.y, v2.y);
        r.z = fmaxf(r.z, v2.z); r.w = fmaxf(r.w, v2.w);
      }
      pmm[B] = r;
    }
  }
  for(int v = B; v < 4608; v += GRID){
    int g = v * 256 + tid;
    int o = g & 31, i = (g >> 5) & 31, rest = g >> 10;
    int pq = rest % 144, ls = rest / 144;
    wt[g] = ((const float2*)A.spec)[(((size_t)(ls * 32 + i) * 32 + o) * 144 + pq)];
  }
  if(B == GRID - 1){
    for(int s = tid; s < 512; s += 256){
      int jt = s >> 6, l2 = s & 63;
      int c = l2 & 15, qq = l2 >> 4;
      #pragma unroll
      for(int e = 0; e < 8; ++e){
        float wv = A.fc1w[(qq * 8 + e) * 128 + jt * 16 + c];
        ushort_t hi = f2b(wv);
        WB[(jt * 64 + l2) * 8 + e] = hi;
        WB[4096 + (jt * 64 + l2) * 8 + e] = f2b(wv - b2f(hi));
      }
    }
    for(int s = tid; s < 8192; s += 256){
      int l2 = s >> 11, rem = s & 2047, limb = rem >> 10, rem2 = rem & 1023;
      int half = rem2 >> 9, le = rem2 & 511, lane2 = le >> 3, e = le & 7;
      int c = half * 16 + (lane2 & 15);
      int i = (lane2 >> 4) * 8 + e;
      float wv = A.convw[((size_t)l2 * 32 + c) * 32 + i] * 4096.0f;
      ushort_t hi = f2b(wv);
      WA[s] = limb ? f2b(wv - b2f(hi)) : hi;
    }
  }
  gbar(bcnt, bgen);

  //======== phase 1: vbuild (V fragments + fc0) — verbatim R9 body ========
  for(int v = B; v < 1024; v += GRID){
    ushort_t* lds1 = (ushort_t*)SMEM;
    float4*   mmvp = (float4*)(SMEM + 37376);
    if(tid < 64){
      float4 a = pmm[tid], c = pmm[tid + 64];
      float mn0 = fminf(a.x, c.x), mn1 = fminf(a.y, c.y);
      float mx0 = fmaxf(a.z, c.z), mx1 = fmaxf(a.w, c.w);
      for(int off = 32; off > 0; off >>= 1){
        mn0 = fminf(mn0, __shfl_down(mn0, off));
        mn1 = fminf(mn1, __shfl_down(mn1, off));
        mx0 = fmaxf(mx0, __shfl_down(mx0, off));
        mx1 = fmaxf(mx1, __shfl_down(mx1, off));
      }
      if(tid == 0) *mmvp = make_float4(mn0, mn1, mx0, mx1);
    }
    __syncthreads();
    const int nl = tid & 31, pt = tid >> 5;
    const int b = v >> 8;
    const int nblk = v & 255;
    const int n = nblk * 32 + nl;
    float4 mmv = *mmvp;
    float mn0 = mmv.x, mn1 = mmv.y, mx0 = mmv.z, mx1 = mmv.w;
    float x0 = A.x[(size_t)(b * NN + n) * 2]     - mn0;
    float x1 = A.x[(size_t)(b * NN + n) * 2 + 1] - mn1;
    float sp = x0 * (6.28f / (mx0 - mn0));
    float sq = x1 * (6.28f / (mx1 - mn1));
    float cx, sx, cy, sy;
    sincosf(sp, &sx, &cx);
    sincosf(sq, &sy, &cy);
    int j0 = pt * 3;
    int j1 = (j0 + 3 < 23) ? j0 + 3 : 23;
    float ky0 = (j0 < 12) ? (float)j0 : (float)(j0 - 23);
    float cb2, sb2;
    sincosf(ky0 * sq, &sb2, &cb2);
    for(int j = j0; j < j1; ++j){
      float ca = 1.0f, sa = 0.0f;
      #pragma unroll
      for(int i = 0; i < 24; ++i){
        float vr = ca * cb2 - sa * sb2;
        float vi = -(sa * cb2 + ca * sb2);
        int t = j * 24 + i;
        int k = repk(t);
        if(k >= 0){
          lds1[nl * 584 + k]       = f2b(vr);
          lds1[nl * 584 + 288 + k] = f2b(vi);
        }
        float cn = ca * cx - sa * sx;
        float sn = sa * cx + ca * sx;
        if(i == 11) sn = -sn;
        ca = cn; sa = sn;
      }
      float cbn = cb2 * cy - sb2 * sy;
      float sbn = sb2 * cy + cb2 * sy;
      cb2 = cbn; sb2 = sbn;
    }
    __syncthreads();
    #pragma unroll
    for(int r = 0; r < 9; ++r){
      int c = tid + 256 * r;
      int t16 = c / 1152;
      int c2 = c - t16 * 1152;
      int kk = c2 >> 6;
      int rem = c2 & 63;
      int q = rem >> 4, n15 = rem & 15;
      short8 vv = *(const short8*)(lds1 + (t16 * 16 + n15) * 584 + kk * 32 + q * 8);
      *(short8*)(VTF + ((size_t)((b * 512 + nblk * 2 + t16) * 18 + kk)) * 512
                 + (q * 16 + n15) * 8) = vv;
    }
    #pragma unroll
    for(int r = 0; r < 9; ++r){
      int c = tid + 256 * r;
      int st = c >> 6;
      int rem = c & 63;
      int q = rem >> 4, srow = rem & 15;
      int sg = st * 16 + srow;
      int s = (sg < 288) ? sg : sg - 288;
      int sinh_ = (sg >= 288);
      int p2 = s / 12, qq = s - p2 * 12;
      int t = p2 * 23 + qq;
      int k = repk(t);
      unsigned short flip = 0;
      if(k < 0){ k = repk(partner(t)); if(sinh_) flip = 0x8000; }
      int col = sinh_ ? 288 + k : k;
      ushort_t tmp[8];
      #pragma unroll
      for(int e = 0; e < 8; ++e)
        tmp[e] = lds1[(q * 8 + e) * 584 + col] ^ flip;
      *(short8*)(AF + ((size_t)((b * 36 + st) * 256 + nblk)) * 512
                 + (q * 16 + srow) * 8) = *(short8*)tmp;
    }
    #pragma unroll
    for(int rr = 0; rr < 4; ++rr){
      int c2 = pt + rr * 8;
      float val = A.fc0b[c2] + x0 * A.fc0w[c2] + x1 * A.fc0w[32 + c2];
      ushort_t hi = f2b(val), lo = f2b(val - b2f(hi));
      int half = c2 >> 4, cl = c2 & 15;
      hbB0[(((size_t)(b * 2 + half) * 256 + nblk) * 512) + ((nl >> 3) * 16 + cl) * 8 + (nl & 7)] = hi;
      size_t ca = ((size_t)(b * 512 + nblk * 2 + (nl >> 4))) * 512
                + ((c2 >> 3) * 16 + (nl & 15)) * 8 + (c2 & 7);
      hcH0[ca] = hi; hcL0[ca] = lo;
    }
    __syncthreads();
  }
  gbar(bcnt, bgen);

  //======== layer loop ========
  for(int l = 0; l < 4; ++l){
    ushort_t* hbBi = (l & 1) ? hbB1 : hbB0;
    ushort_t* hbBo = (l & 1) ? hbB0 : hbB1;
    ushort_t* hciH = (l & 1) ? hcH1 : hcH0;
    ushort_t* hciL = (l & 1) ? hcL1 : hcL0;
    ushort_t* hcoH = (l & 1) ? hcH0 : hcH1;
    ushort_t* hcoL = (l & 1) ? hcL0 : hcL1;

    // ---- F: forward transform (verbatim R9 k_fwd body) ----
    {
      float* red = (float*)SMEM;
      for(int v = B; v < 1152; v += GRID){
        int stp = v >> 6;
        int rem = v & 63;
        int ks = rem >> 2;
        int b  = rem & 3;
        const int w = tid >> 6, lane = tid & 63;
        const int row = lane & 15, q = lane >> 4;
        const int st0 = stp * 2;
        const size_t abase0 = ((size_t)(b * 36 + st0) * 256) * 512 + (q * 16 + row) * 8;
        const size_t abase1 = abase0 + (size_t)256 * 512;
        const size_t hB0o = ((size_t)(b * 2 + 0) * 256) * 512 + (size_t)lane * 8;
        const size_t hB1o = ((size_t)(b * 2 + 1) * 256) * 512 + (size_t)lane * 8;
        floatx4 aA0 = {0.f,0.f,0.f,0.f}, aA1 = {0.f,0.f,0.f,0.f};
        floatx4 aB0 = {0.f,0.f,0.f,0.f}, aB1 = {0.f,0.f,0.f,0.f};
        #pragma unroll
        for(int kk = 0; kk < 4; ++kk){
          int g = ks * 16 + w * 4 + kk;
          short8 A0 = *(const short8*)(AF + abase0 + (size_t)g * 512);
          short8 A1 = *(const short8*)(AF + abase1 + (size_t)g * 512);
          short8 B0 = *(const short8*)(hbBi + hB0o + (size_t)g * 512);
          short8 B1 = *(const short8*)(hbBi + hB1o + (size_t)g * 512);
          aA0 = __builtin_amdgcn_mfma_f32_16x16x32_bf16(A0, B0, aA0, 0, 0, 0);
          aA1 = __builtin_amdgcn_mfma_f32_16x16x32_bf16(A0, B1, aA1, 0, 0, 0);
          aB0 = __builtin_amdgcn_mfma_f32_16x16x32_bf16(A1, B0, aB0, 0, 0, 0);
          aB1 = __builtin_amdgcn_mfma_f32_16x16x32_bf16(A1, B1, aB1, 0, 0, 0);
        }
        const int e = tid, eo = tid & 31;
        #pragma unroll
        for(int r = 0; r < 4; ++r){
          int rrow = q * 4 + r;
          red[w * 512 + rrow * 32 + row]      = aA0[r];
          red[w * 512 + rrow * 32 + 16 + row] = aA1[r];
        }
        __syncthreads();
        {
          float v0 = red[e] + red[512 + e] + red[1024 + e] + red[1536 + e];
          float v1 = red[e + 256] + red[512 + e + 256] + red[1024 + e + 256] + red[1536 + e + 256];
          size_t r0 = (size_t)(b * 576 + st0 * 16 + (e >> 5));
          xp[(r0 * 16 + ks) * 32 + eo]       = v0;
          xp[((r0 + 8) * 16 + ks) * 32 + eo] = v1;
        }
        __syncthreads();
        #pragma unroll
        for(int r = 0; r < 4; ++r){
          int rrow = q * 4 + r;
          red[w * 512 + rrow * 32 + row]      = aB0[r];
          red[w * 512 + rrow * 32 + 16 + row] = aB1[r];
        }
        __syncthreads();
        {
          float v0 = red[e] + red[512 + e] + red[1024 + e] + red[1536 + e];
          float v1 = red[e + 256] + red[512 + e + 256] + red[1024 + e + 256] + red[1536 + e + 256];
          size_t r0 = (size_t)(b * 576 + (st0 + 1) * 16 + (e >> 5));
          xp[(r0 * 16 + ks) * 32 + eo]       = v0;
          xp[((r0 + 8) * 16 + ks) * 32 + eo] = v1;
        }
        __syncthreads();
      }
    }
    gbar(bcnt, bgen);

    // ---- M: mix + fold -> ghif + glof (verbatim R9 k_mixg body) ----
    {
      float* Xs  = (float*)SMEM;     // [2][64]
      float* FrP = Xs + 128;         // [2][2][32]
      float* FiP = FrP + 128;
      for(int v = B; v < 1152; v += GRID){
        int k = v >> 2, b = v & 3;
        const int wv_ = tid >> 6, lane = tid & 63;
        const int t = repT(k);
        const int j = t / 24, i = t - j * 24;
        const int u = partner(t);
        const bool unpaired = (i == 12) || (u == t);
        const int idxT = (t < 288) ? t : 575 - t;  const bool cfT = (t >= 288);
        const int idxU = (u < 288) ? u : 575 - u;  const bool cfU = (u >= 288);
        {
          const int m = wv_ & 1, hf = wv_ >> 1;
          int idx = m ? idxU : idxT;
          int rrow = hf ? 288 + idx : idx;
          const float* sb = xp + (size_t)(b * 576 + rrow) * 512;
          float4 a = *(const float4*)(sb + lane * 4);
          float4 c = *(const float4*)(sb + 256 + lane * 4);
          a.x += c.x; a.y += c.y; a.z += c.z; a.w += c.w;
          #pragma unroll
          for(int mk = 8; mk <= 32; mk <<= 1){
            a.x += __shfl_xor(a.x, mk);
            a.y += __shfl_xor(a.y, mk);
            a.z += __shfl_xor(a.z, mk);
            a.w += __shfl_xor(a.w, mk);
          }
          if(lane < 8){
            int o0 = hf * 32 + lane * 4;
            Xs[m * 64 + o0 + 0] = a.x;
            Xs[m * 64 + o0 + 1] = a.y;
            Xs[m * 64 + o0 + 2] = a.z;
            Xs[m * 64 + o0 + 3] = a.w;
          }
        }
        __syncthreads();
        {
          const int m = wv_ & 1, ih = wv_ >> 1;
          int idx = m ? idxU : idxT;
          int p2 = idx / 12, qq = idx - p2 * 12;
          int sel = (p2 < 12) ? 0 : 1;
          int pq = (p2 % 12) * 12 + qq;
          const float2* wb = wt + ((size_t)((l * 2 + sel) * 144 + pq)) * 1024;
          if(lane < 32){
            const int o = lane;
            float fr = 0.f, fi = 0.f;
            #pragma unroll
            for(int ii = 0; ii < 16; ++ii){
              int i2 = ih * 16 + ii;
              float xr = Xs[m * 64 + i2], xi = Xs[m * 64 + 32 + i2];
              float2 wvv = wb[i2 * 32 + o];
              fr += xr * wvv.x - xi * wvv.y;
              fi += xr * wvv.y + xi * wvv.x;
            }
            FrP[(m * 2 + ih) * 32 + o] = fr;
            FiP[(m * 2 + ih) * 32 + o] = fi;
          }
        }
        __syncthreads();
        if(wv_ == 0 && lane < 32){
          const int c = lane;
          const int srcT = cfT ? 31 - c : c;
          const int srcU = cfU ? 31 - c : c;
          float fax = FrP[srcT]      + FrP[32 + srcT];
          float fay = FiP[srcT]      + FiP[32 + srcT];
          float fbx = FrP[64 + srcU] + FrP[96 + srcU];
          float fby = FiP[64 + srcU] + FiP[96 + srcU];
          float gr = fax;
          float gi = cfT ? -fay : fay;
          if(!unpaired){
            gr += fbx;
            gi -= (cfU ? -fby : fby);
          }
          unsigned short hr = f2b(gr); float lr = gr - b2f(hr);
          unsigned short hi2 = f2b(gi); float li = gi - b2f(hi2);
          int hhc = c >> 4, cl = c & 15;
          int kk1 = k >> 5, q1 = (k >> 3) & 3, e1 = k & 7;
          size_t fb2 = (size_t)(b * 2 + hhc) * 18;
          size_t off = (size_t)(q1 * 16 + cl) * 8 + e1;
          ghif[(fb2 + kk1) * 512 + off]     = hr;
          ghif[(fb2 + 9 + kk1) * 512 + off] = hi2;
          glof[(fb2 + kk1) * 512 + off]     = f2b(lr);
          glof[(fb2 + 9 + kk1) * 512 + off] = f2b(li);
        }
        __syncthreads();
      }
    }
    gbar(bcnt, bgen);

    // ---- I: inverse transform + conv fold (verbatim R9 k_inv body) ----
    {
      for(int v = B; v < 1024; v += GRID){
        int bx = v & 255, b = v >> 8;
        const int lane = tid & 63, w = tid >> 6;
        const int tl = w >> 1;
        const int hh = w & 1;
        const int row = lane & 15, q = lane >> 4;
        const int t16 = bx * 2 + tl;
        const ushort_t* vb = VTF + ((size_t)(b * 512 + t16) * 18) * 512 + lane * 8;
        const ushort_t* gh = ghif + ((size_t)(b * 2 + hh) * 18) * 512 + lane * 8;
        const ushort_t* gl = glof + ((size_t)(b * 2 + hh) * 18) * 512 + lane * 8;
        floatx4 ah = {0.f,0.f,0.f,0.f}, al = {0.f,0.f,0.f,0.f};
        #pragma unroll
        for(int kk = 0; kk < 18; ++kk){
          short8 Bv = *(const short8*)(vb + (size_t)kk * 512);
          short8 Ah = *(const short8*)(gh + (size_t)kk * 512);
          short8 Al = *(const short8*)(gl + (size_t)kk * 512);
          ah = __builtin_amdgcn_mfma_f32_16x16x32_bf16(Ah, Bv, ah, 0, 0, 0);
          al = __builtin_amdgcn_mfma_f32_16x16x32_bf16(Al, Bv, al, 0, 0, 0);
        }
        {
          short8 Whi = *(const short8*)(WA + ((size_t)((l * 2 + 0) * 2 + hh)) * 512 + lane * 8);
          short8 Wlo = *(const short8*)(WA + ((size_t)((l * 2 + 1) * 2 + hh)) * 512 + lane * 8);
          short8 Bhi = *(const short8*)(hciH + ((size_t)(b * 512 + t16)) * 512 + lane * 8);
          short8 Blo = *(const short8*)(hciL + ((size_t)(b * 512 + t16)) * 512 + lane * 8);
          ah = __builtin_amdgcn_mfma_f32_16x16x32_bf16(Whi, Bhi, ah, 0, 0, 0);
          al = __builtin_amdgcn_mfma_f32_16x16x32_bf16(Wlo, Bhi, al, 0, 0, 0);
          ah = __builtin_amdgcn_mfma_f32_16x16x32_bf16(Whi, Blo, ah, 0, 0, 0);
        }
        floatx4 accF = ah + al;
        const float sc = 2.0f / 8192.0f;
        float cb[4];
        #pragma unroll
        for(int r = 0; r < 4; ++r) cb[r] = A.convb[l * 32 + hh * 16 + q * 4 + r];
        if(l < 3){
          const int n = bx * 32 + tl * 16 + row;
          const int g2 = n >> 5, qb = (n >> 3) & 3, e2 = n & 7;
          #pragma unroll
          for(int r = 0; r < 4; ++r){
            int c = hh * 16 + q * 4 + r;
            float vv = gelu_f(accF[r] * sc + cb[r]);
            ushort_t hi = f2b(vv), lo = f2b(vv - b2f(hi));
            hbBo[(((size_t)(b * 2 + hh) * 256 + g2) * 512) + (qb * 16 + (q * 4 + r)) * 8 + e2] = hi;
            size_t ca = ((size_t)(b * 512 + t16)) * 512 + ((c >> 3) * 16 + row) * 8 + (c & 7);
            hcoH[ca] = hi; hcoL[ca] = lo;
          }
        } else {
          ushort_t* hHi = (ushort_t*)SMEM;          // [32][36]
          ushort_t* hLo = hHi + 1152;
          float*    prt = (float*)(SMEM + 4608);    // [2][32]
          {
            ushort_t H[4], L[4];
            #pragma unroll
            for(int r = 0; r < 4; ++r){
              float vv = accF[r] * sc + cb[r];
              H[r] = f2b(vv); L[r] = f2b(vv - b2f(H[r]));
            }
            uint2 uu;
            uu.x = (unsigned)H[0] | ((unsigned)H[1] << 16);
            uu.y = (unsigned)H[2] | ((unsigned)H[3] << 16);
            *(uint2*)&hHi[(tl * 16 + row) * 36 + hh * 16 + q * 4] = uu;
            uu.x = (unsigned)L[0] | ((unsigned)L[1] << 16);
            uu.y = (unsigned)L[2] | ((unsigned)L[3] << 16);
            *(uint2*)&hLo[(tl * 16 + row) * 36 + hh * 16 + q * 4] = uu;
          }
          __syncthreads();
          const int cl = row;
          short8 Ahi = *(const short8*)&hHi[(tl * 16 + cl) * 36 + q * 8];
          short8 Alo = *(const short8*)&hLo[(tl * 16 + cl) * 36 + q * 8];
          float S0 = 0.f, S1 = 0.f, S2 = 0.f, S3 = 0.f;
          #pragma unroll
          for(int jt2 = 0; jt2 < 4; ++jt2){
            int jt = hh * 4 + jt2;
            short8 Bhi = *(const short8*)(WB + (jt * 64 + lane) * 8);
            short8 Blo = *(const short8*)(WB + 4096 + (jt * 64 + lane) * 8);
            floatx4 acc = {0.f, 0.f, 0.f, 0.f};
            acc = __builtin_amdgcn_mfma_f32_16x16x32_bf16(Ahi, Bhi, acc, 0, 0, 0);
            acc = __builtin_amdgcn_mfma_f32_16x16x32_bf16(Alo, Bhi, acc, 0, 0, 0);
            acc = __builtin_amdgcn_mfma_f32_16x16x32_bf16(Ahi, Blo, acc, 0, 0, 0);
            float bv = A.fc1b[jt * 16 + cl], wv2 = A.fc2w[jt * 16 + cl];
            S0 = fmaf(gelu_f(acc[0] + bv), wv2, S0);
            S1 = fmaf(gelu_f(acc[1] + bv), wv2, S1);
            S2 = fmaf(gelu_f(acc[2] + bv), wv2, S2);
            S3 = fmaf(gelu_f(acc[3] + bv), wv2, S3);
          }
          #pragma unroll
          for(int off = 8; off; off >>= 1){
            S0 += __shfl_xor(S0, off, 16);
            S1 += __shfl_xor(S1, off, 16);
            S2 += __shfl_xor(S2, off, 16);
            S3 += __shfl_xor(S3, off, 16);
          }
          if(cl == 0){
            int pb = tl * 16 + q * 4;
            prt[hh * 32 + pb + 0] = S0;
            prt[hh * 32 + pb + 1] = S1;
            prt[hh * 32 + pb + 2] = S2;
            prt[hh * 32 + pb + 3] = S3;
          }
          __syncthreads();
          if(tid < 32)
            A.out[(size_t)b * NN + bx * 32 + tid] = prt[tid] + prt[32 + tid] + A.fc2b[0];
          __syncthreads();
        }
      }
    }
    if(l < 3) gbar(bcnt, bgen);
  }
}

// ---------- launch ----------
extern "C" void kernel_launch(void* const* d_in, const int* in_sizes, int n_in,
                              void* d_out, int out_size, void* d_ws, size_t ws_size,
                              hipStream_t stream)
{
  MArgs ma;
  ma.x     = (const float*)d_in[0];
  ma.fc0w  = (const float*)d_in[1];
  ma.fc0b  = (const float*)d_in[2];
  ma.spec  = (const float*)d_in[3];
  ma.convw = (const float*)d_in[4];
  ma.convb = (const float*)d_in[5];
  ma.fc1w  = (const float*)d_in[6];
  ma.fc1b  = (const float*)d_in[7];
  ma.fc2w  = (const float*)d_in[8];
  ma.fc2b  = (const float*)d_in[9];
  ma.out   = (float*)d_out;
  ma.ws    = (char*)d_ws;
  // zero the barrier words (stream-ordered, graph-capture-safe)
  hipMemsetAsync((char*)d_ws + OFF_BAR, 0, 8, stream);
  hipLaunchKernelGGL(k_mega, dim3(GRID), dim3(256), 0, stream, ma);
  (void)in_sizes; (void)n_in; (void)out_size; (void)ws_size;
}

// Round 11
// 1081.165 us; speedup vs baseline: 1.2844x; 1.2844x over previous
//
#include <hip/hip_runtime.h>
#include <cmath>

#define NB 4
#define NN 8192
#define CH 32
#define GRID 512

typedef short short8 __attribute__((ext_vector_type(8)));
typedef float floatx4 __attribute__((ext_vector_type(4)));
typedef unsigned short ushort_t;

// ---------- helpers ----------
__device__ __forceinline__ unsigned short f2b(float f){
  unsigned u = __float_as_uint(f);
  u = u + 0x7FFFu + ((u >> 16) & 1u);   // RNE
  return (unsigned short)(u >> 16);
}
__device__ __forceinline__ float b2f(unsigned short h){
  return __uint_as_float(((unsigned)h) << 16);
}
__device__ __forceinline__ float gelu_f(float v){
  return 0.5f * v * (1.0f + erff(v * 0.70710678118654752440f));
}
__device__ __forceinline__ int repk(int t){
  int j = t / 24, i = t - j * 24;
  if(j == 0)  return (i <= 12) ? i : -1;
  if(j <= 11) return 13 + (j - 1) * 24 + i;
  return (i == 12) ? 277 + (j - 12) : -1;
}
__device__ __forceinline__ int partner(int t){
  int j = t / 24, i = t - j * 24;
  return ((23 - j) % 23) * 24 + ((24 - i) % 24);
}
__device__ __forceinline__ int repT(int k){
  if(k < 13) return k;
  if(k < 277){ int m = k - 13; return (m / 24 + 1) * 24 + (m % 24); }
  return (k - 277 + 12) * 24 + 12;
}

// ---------- hand-rolled grid barrier, v2 (cheap-poll + 2-level arrival) ----------
// R10's barrier was correct but cost ~98us: acquire-poll every ~0.2us -> buffer_inv
// flood from 511 waiters + 512-way RMW contention on one line. v2: (1) s_sleep(64)
// (~1.7us) between acquire polls (8x fewer invalidates); (2) arrival via 8 padded
// sub-counters (64 blocks each) -> root(8) -> gen. Release/acquire transitivity:
// sub resets visible via root ACQ_REL chain before gen RELEASE; waiters ACQUIRE gen.
// Fence structure identical to the R10-proven version.
__device__ __forceinline__ void gbar(unsigned* bar, int B){
  __syncthreads();
  if(threadIdx.x == 0){
    unsigned* sub  = bar + (B & 7) * 32;   // 128-byte spaced counters
    unsigned* root = bar + 256;
    unsigned* gen  = bar + 257;
    unsigned g = __hip_atomic_load(gen, __ATOMIC_RELAXED, __HIP_MEMORY_SCOPE_AGENT);
    __threadfence();
    unsigned a = __hip_atomic_fetch_add(sub, 1u, __ATOMIC_ACQ_REL, __HIP_MEMORY_SCOPE_AGENT);
    if(a == (unsigned)(GRID / 8) - 1u){
      __hip_atomic_store(sub, 0u, __ATOMIC_RELAXED, __HIP_MEMORY_SCOPE_AGENT);
      unsigned r = __hip_atomic_fetch_add(root, 1u, __ATOMIC_ACQ_REL, __HIP_MEMORY_SCOPE_AGENT);
      if(r == 7u){
        __hip_atomic_store(root, 0u, __ATOMIC_RELAXED, __HIP_MEMORY_SCOPE_AGENT);
        __hip_atomic_store(gen, g + 1u, __ATOMIC_RELEASE, __HIP_MEMORY_SCOPE_AGENT);
      }
    }
    while(__hip_atomic_load(gen, __ATOMIC_ACQUIRE, __HIP_MEMORY_SCOPE_AGENT) == g)
      __builtin_amdgcn_s_sleep(64);
    __threadfence();
  }
  __syncthreads();
}

// ---------- workspace offsets ----------
static constexpr size_t OFF_PMM = 0;
static constexpr size_t OFF_WT  = 4096;
static constexpr size_t OFF_AF  = OFF_WT  + 9437184;
static constexpr size_t OFF_VTF = OFF_AF  + 37748736;
static constexpr size_t OFF_HB0 = OFF_VTF + 37748736;
static constexpr size_t OFF_HB1 = OFF_HB0 + 2097152;
static constexpr size_t OFF_HC0 = OFF_HB1 + 2097152;
static constexpr size_t OFF_HC1 = OFF_HC0 + 2097152;
static constexpr size_t OFF_HL0 = OFF_HC1 + 2097152;
static constexpr size_t OFF_HL1 = OFF_HL0 + 2097152;
static constexpr size_t OFF_XP  = OFF_HL1 + 2097152;
static constexpr size_t OFF_GHF = OFF_XP  + 4718592;
static constexpr size_t OFF_GLO = OFF_GHF + 147456;
static constexpr size_t OFF_WB  = OFF_GLO + 147456;
static constexpr size_t OFF_WA  = OFF_WB  + 16384;
static constexpr size_t OFF_BAR = OFF_WA  + 16384;

struct MArgs {
  const float *x, *fc0w, *fc0b, *spec, *convw, *convb, *fc1w, *fc1b, *fc2w, *fc2b;
  float* out;
  char* ws;
};

// ================= persistent mega-kernel, hand barrier v2 =================
// 512 blocks x 256 thr, launch_bounds(256,2): LDS 37.4KB -> >=2 blocks/CU
// guaranteed -> all 512 co-resident. Phase bodies VERBATIM R9/R10 (bit-exact).
__global__ __launch_bounds__(256, 2) void k_mega(MArgs A)
{
  __shared__ alignas(16) char SMEM[37392];
  const int tid = threadIdx.x;
  const int B   = blockIdx.x;

  float4*   pmm  = (float4*)(A.ws + OFF_PMM);
  float2*   wt   = (float2*)(A.ws + OFF_WT);
  ushort_t* AF   = (ushort_t*)(A.ws + OFF_AF);
  ushort_t* VTF  = (ushort_t*)(A.ws + OFF_VTF);
  ushort_t* hbB0 = (ushort_t*)(A.ws + OFF_HB0);
  ushort_t* hbB1 = (ushort_t*)(A.ws + OFF_HB1);
  ushort_t* hcH0 = (ushort_t*)(A.ws + OFF_HC0);
  ushort_t* hcH1 = (ushort_t*)(A.ws + OFF_HC1);
  ushort_t* hcL0 = (ushort_t*)(A.ws + OFF_HL0);
  ushort_t* hcL1 = (ushort_t*)(A.ws + OFF_HL1);
  float*    xp   = (float*)(A.ws + OFF_XP);
  ushort_t* ghif = (ushort_t*)(A.ws + OFF_GHF);
  ushort_t* glof = (ushort_t*)(A.ws + OFF_GLO);
  ushort_t* WB   = (ushort_t*)(A.ws + OFF_WB);
  ushort_t* WA   = (ushort_t*)(A.ws + OFF_WA);
  unsigned* bar  = (unsigned*)(A.ws + OFF_BAR);

  //======== phase 0: minmax partials + spec reorder + WB/WA ========
  if(B < 128){
    float4* wp = (float4*)SMEM;
    int g = B * 256 + tid;
    float a = A.x[(size_t)g * 2], b = A.x[(size_t)g * 2 + 1];
    float mn0 = a, mx0 = a, mn1 = b, mx1 = b;
    for(int off = 32; off > 0; off >>= 1){
      mn0 = fminf(mn0, __shfl_down(mn0, off));
      mx0 = fmaxf(mx0, __shfl_down(mx0, off));
      mn1 = fminf(mn1, __shfl_down(mn1, off));
      mx1 = fmaxf(mx1, __shfl_down(mx1, off));
    }
    if((tid & 63) == 0) wp[tid >> 6] = make_float4(mn0, mn1, mx0, mx1);
    __syncthreads();
    if(tid == 0){
      float4 r = wp[0];
      for(int i2 = 1; i2 < 4; ++i2){
        float4 v2 = wp[i2];
        r.x = fminf(r.x, v2.x); r.y = fminf(r.y, v2.y);
        r.z = fmaxf(r.z, v2.z); r.w = fmaxf(r.w, v2.w);
      }
      pmm[B] = r;
    }
  }
  for(int v = B; v < 4608; v += GRID){
    int g = v * 256 + tid;
    int o = g & 31, i = (g >> 5) & 31, rest = g >> 10;
    int pq = rest % 144, ls = rest / 144;
    wt[g] = ((const float2*)A.spec)[(((size_t)(ls * 32 + i) * 32 + o) * 144 + pq)];
  }
  if(B == GRID - 1){
    for(int s = tid; s < 512; s += 256){
      int jt = s >> 6, l2 = s & 63;
      int c = l2 & 15, qq = l2 >> 4;
      #pragma unroll
      for(int e = 0; e < 8; ++e){
        float wv = A.fc1w[(qq * 8 + e) * 128 + jt * 16 + c];
        ushort_t hi = f2b(wv);
        WB[(jt * 64 + l2) * 8 + e] = hi;
        WB[4096 + (jt * 64 + l2) * 8 + e] = f2b(wv - b2f(hi));
      }
    }
    for(int s = tid; s < 8192; s += 256){
      int l2 = s >> 11, rem = s & 2047, limb = rem >> 10, rem2 = rem & 1023;
      int half = rem2 >> 9, le = rem2 & 511, lane2 = le >> 3, e = le & 7;
      int c = half * 16 + (lane2 & 15);
      int i = (lane2 >> 4) * 8 + e;
      float wv = A.convw[((size_t)l2 * 32 + c) * 32 + i] * 4096.0f;
      ushort_t hi = f2b(wv);
      WA[s] = limb ? f2b(wv - b2f(hi)) : hi;
    }
  }
  gbar(bar, B);

  //======== phase 1: vbuild (V fragments + fc0) — verbatim R9 body ========
  for(int v = B; v < 1024; v += GRID){
    ushort_t* lds1 = (ushort_t*)SMEM;
    float4*   mmvp = (float4*)(SMEM + 37376);
    if(tid < 64){
      float4 a = pmm[tid], c = pmm[tid + 64];
      float mn0 = fminf(a.x, c.x), mn1 = fminf(a.y, c.y);
      float mx0 = fmaxf(a.z, c.z), mx1 = fmaxf(a.w, c.w);
      for(int off = 32; off > 0; off >>= 1){
        mn0 = fminf(mn0, __shfl_down(mn0, off));
        mn1 = fminf(mn1, __shfl_down(mn1, off));
        mx0 = fmaxf(mx0, __shfl_down(mx0, off));
        mx1 = fmaxf(mx1, __shfl_down(mx1, off));
      }
      if(tid == 0) *mmvp = make_float4(mn0, mn1, mx0, mx1);
    }
    __syncthreads();
    const int nl = tid & 31, pt = tid >> 5;
    const int b = v >> 8;
    const int nblk = v & 255;
    const int n = nblk * 32 + nl;
    float4 mmv = *mmvp;
    float mn0 = mmv.x, mn1 = mmv.y, mx0 = mmv.z, mx1 = mmv.w;
    float x0 = A.x[(size_t)(b * NN + n) * 2]     - mn0;
    float x1 = A.x[(size_t)(b * NN + n) * 2 + 1] - mn1;
    float sp = x0 * (6.28f / (mx0 - mn0));
    float sq = x1 * (6.28f / (mx1 - mn1));
    float cx, sx, cy, sy;
    sincosf(sp, &sx, &cx);
    sincosf(sq, &sy, &cy);
    int j0 = pt * 3;
    int j1 = (j0 + 3 < 23) ? j0 + 3 : 23;
    float ky0 = (j0 < 12) ? (float)j0 : (float)(j0 - 23);
    float cb2, sb2;
    sincosf(ky0 * sq, &sb2, &cb2);
    for(int j = j0; j < j1; ++j){
      float ca = 1.0f, sa = 0.0f;
      #pragma unroll
      for(int i = 0; i < 24; ++i){
        float vr = ca * cb2 - sa * sb2;
        float vi = -(sa * cb2 + ca * sb2);
        int t = j * 24 + i;
        int k = repk(t);
        if(k >= 0){
          lds1[nl * 584 + k]       = f2b(vr);
          lds1[nl * 584 + 288 + k] = f2b(vi);
        }
        float cn = ca * cx - sa * sx;
        float sn = sa * cx + ca * sx;
        if(i == 11) sn = -sn;
        ca = cn; sa = sn;
      }
      float cbn = cb2 * cy - sb2 * sy;
      float sbn = sb2 * cy + cb2 * sy;
      cb2 = cbn; sb2 = sbn;
    }
    __syncthreads();
    #pragma unroll
    for(int r = 0; r < 9; ++r){
      int c = tid + 256 * r;
      int t16 = c / 1152;
      int c2 = c - t16 * 1152;
      int kk = c2 >> 6;
      int rem = c2 & 63;
      int q = rem >> 4, n15 = rem & 15;
      short8 vv = *(const short8*)(lds1 + (t16 * 16 + n15) * 584 + kk * 32 + q * 8);
      *(short8*)(VTF + ((size_t)((b * 512 + nblk * 2 + t16) * 18 + kk)) * 512
                 + (q * 16 + n15) * 8) = vv;
    }
    #pragma unroll
    for(int r = 0; r < 9; ++r){
      int c = tid + 256 * r;
      int st = c >> 6;
      int rem = c & 63;
      int q = rem >> 4, srow = rem & 15;
      int sg = st * 16 + srow;
      int s = (sg < 288) ? sg : sg - 288;
      int sinh_ = (sg >= 288);
      int p2 = s / 12, qq = s - p2 * 12;
      int t = p2 * 23 + qq;
      int k = repk(t);
      unsigned short flip = 0;
      if(k < 0){ k = repk(partner(t)); if(sinh_) flip = 0x8000; }
      int col = sinh_ ? 288 + k : k;
      ushort_t tmp[8];
      #pragma unroll
      for(int e = 0; e < 8; ++e)
        tmp[e] = lds1[(q * 8 + e) * 584 + col] ^ flip;
      *(short8*)(AF + ((size_t)((b * 36 + st) * 256 + nblk)) * 512
                 + (q * 16 + srow) * 8) = *(short8*)tmp;
    }
    #pragma unroll
    for(int rr = 0; rr < 4; ++rr){
      int c2 = pt + rr * 8;
      float val = A.fc0b[c2] + x0 * A.fc0w[c2] + x1 * A.fc0w[32 + c2];
      ushort_t hi = f2b(val), lo = f2b(val - b2f(hi));
      int half = c2 >> 4, cl = c2 & 15;
      hbB0[(((size_t)(b * 2 + half) * 256 + nblk) * 512) + ((nl >> 3) * 16 + cl) * 8 + (nl & 7)] = hi;
      size_t ca = ((size_t)(b * 512 + nblk * 2 + (nl >> 4))) * 512
                + ((c2 >> 3) * 16 + (nl & 15)) * 8 + (c2 & 7);
      hcH0[ca] = hi; hcL0[ca] = lo;
    }
    __syncthreads();
  }
  gbar(bar, B);

  //======== layer loop ========
  for(int l = 0; l < 4; ++l){
    ushort_t* hbBi = (l & 1) ? hbB1 : hbB0;
    ushort_t* hbBo = (l & 1) ? hbB0 : hbB1;
    ushort_t* hciH = (l & 1) ? hcH1 : hcH0;
    ushort_t* hciL = (l & 1) ? hcL1 : hcL0;
    ushort_t* hcoH = (l & 1) ? hcH0 : hcH1;
    ushort_t* hcoL = (l & 1) ? hcL0 : hcL1;

    // ---- F: forward transform (verbatim R9 k_fwd body) ----
    {
      float* red = (float*)SMEM;
      for(int v = B; v < 1152; v += GRID){
        int stp = v >> 6;
        int rem = v & 63;
        int ks = rem >> 2;
        int b  = rem & 3;
        const int w = tid >> 6, lane = tid & 63;
        const int row = lane & 15, q = lane >> 4;
        const int st0 = stp * 2;
        const size_t abase0 = ((size_t)(b * 36 + st0) * 256) * 512 + (q * 16 + row) * 8;
        const size_t abase1 = abase0 + (size_t)256 * 512;
        const size_t hB0o = ((size_t)(b * 2 + 0) * 256) * 512 + (size_t)lane * 8;
        const size_t hB1o = ((size_t)(b * 2 + 1) * 256) * 512 + (size_t)lane * 8;
        floatx4 aA0 = {0.f,0.f,0.f,0.f}, aA1 = {0.f,0.f,0.f,0.f};
        floatx4 aB0 = {0.f,0.f,0.f,0.f}, aB1 = {0.f,0.f,0.f,0.f};
        #pragma unroll
        for(int kk = 0; kk < 4; ++kk){
          int g = ks * 16 + w * 4 + kk;
          short8 A0 = *(const short8*)(AF + abase0 + (size_t)g * 512);
          short8 A1 = *(const short8*)(AF + abase1 + (size_t)g * 512);
          short8 B0 = *(const short8*)(hbBi + hB0o + (size_t)g * 512);
          short8 B1 = *(const short8*)(hbBi + hB1o + (size_t)g * 512);
          aA0 = __builtin_amdgcn_mfma_f32_16x16x32_bf16(A0, B0, aA0, 0, 0, 0);
          aA1 = __builtin_amdgcn_mfma_f32_16x16x32_bf16(A0, B1, aA1, 0, 0, 0);
          aB0 = __builtin_amdgcn_mfma_f32_16x16x32_bf16(A1, B0, aB0, 0, 0, 0);
          aB1 = __builtin_amdgcn_mfma_f32_16x16x32_bf16(A1, B1, aB1, 0, 0, 0);
        }
        const int e = tid, eo = tid & 31;
        #pragma unroll
        for(int r = 0; r < 4; ++r){
          int rrow = q * 4 + r;
          red[w * 512 + rrow * 32 + row]      = aA0[r];
          red[w * 512 + rrow * 32 + 16 + row] = aA1[r];
        }
        __syncthreads();
        {
          float v0 = red[e] + red[512 + e] + red[1024 + e] + red[1536 + e];
          float v1 = red[e + 256] + red[512 + e + 256] + red[1024 + e + 256] + red[1536 + e + 256];
          size_t r0 = (size_t)(b * 576 + st0 * 16 + (e >> 5));
          xp[(r0 * 16 + ks) * 32 + eo]       = v0;
          xp[((r0 + 8) * 16 + ks) * 32 + eo] = v1;
        }
        __syncthreads();
        #pragma unroll
        for(int r = 0; r < 4; ++r){
          int rrow = q * 4 + r;
          red[w * 512 + rrow * 32 + row]      = aB0[r];
          red[w * 512 + rrow * 32 + 16 + row] = aB1[r];
        }
        __syncthreads();
        {
          float v0 = red[e] + red[512 + e] + red[1024 + e] + red[1536 + e];
          float v1 = red[e + 256] + red[512 + e + 256] + red[1024 + e + 256] + red[1536 + e + 256];
          size_t r0 = (size_t)(b * 576 + (st0 + 1) * 16 + (e >> 5));
          xp[(r0 * 16 + ks) * 32 + eo]       = v0;
          xp[((r0 + 8) * 16 + ks) * 32 + eo] = v1;
        }
        __syncthreads();
      }
    }
    gbar(bar, B);

    // ---- M: mix + fold -> ghif + glof (verbatim R9 k_mixg body) ----
    {
      float* Xs  = (float*)SMEM;     // [2][64]
      float* FrP = Xs + 128;         // [2][2][32]
      float* FiP = FrP + 128;
      for(int v = B; v < 1152; v += GRID){
        int k = v >> 2, b = v & 3;
        const int wv_ = tid >> 6, lane = tid & 63;
        const int t = repT(k);
        const int j = t / 24, i = t - j * 24;
        const int u = partner(t);
        const bool unpaired = (i == 12) || (u == t);
        const int idxT = (t < 288) ? t : 575 - t;  const bool cfT = (t >= 288);
        const int idxU = (u < 288) ? u : 575 - u;  const bool cfU = (u >= 288);
        {
          const int m = wv_ & 1, hf = wv_ >> 1;
          int idx = m ? idxU : idxT;
          int rrow = hf ? 288 + idx : idx;
          const float* sb = xp + (size_t)(b * 576 + rrow) * 512;
          float4 a = *(const float4*)(sb + lane * 4);
          float4 c = *(const float4*)(sb + 256 + lane * 4);
          a.x += c.x; a.y += c.y; a.z += c.z; a.w += c.w;
          #pragma unroll
          for(int mk = 8; mk <= 32; mk <<= 1){
            a.x += __shfl_xor(a.x, mk);
            a.y += __shfl_xor(a.y, mk);
            a.z += __shfl_xor(a.z, mk);
            a.w += __shfl_xor(a.w, mk);
          }
          if(lane < 8){
            int o0 = hf * 32 + lane * 4;
            Xs[m * 64 + o0 + 0] = a.x;
            Xs[m * 64 + o0 + 1] = a.y;
            Xs[m * 64 + o0 + 2] = a.z;
            Xs[m * 64 + o0 + 3] = a.w;
          }
        }
        __syncthreads();
        {
          const int m = wv_ & 1, ih = wv_ >> 1;
          int idx = m ? idxU : idxT;
          int p2 = idx / 12, qq = idx - p2 * 12;
          int sel = (p2 < 12) ? 0 : 1;
          int pq = (p2 % 12) * 12 + qq;
          const float2* wb = wt + ((size_t)((l * 2 + sel) * 144 + pq)) * 1024;
          if(lane < 32){
            const int o = lane;
            float fr = 0.f, fi = 0.f;
            #pragma unroll
            for(int ii = 0; ii < 16; ++ii){
              int i2 = ih * 16 + ii;
              float xr = Xs[m * 64 + i2], xi = Xs[m * 64 + 32 + i2];
              float2 wvv = wb[i2 * 32 + o];
              fr += xr * wvv.x - xi * wvv.y;
              fi += xr * wvv.y + xi * wvv.x;
            }
            FrP[(m * 2 + ih) * 32 + o] = fr;
            FiP[(m * 2 + ih) * 32 + o] = fi;
          }
        }
        __syncthreads();
        if(wv_ == 0 && lane < 32){
          const int c = lane;
          const int srcT = cfT ? 31 - c : c;
          const int srcU = cfU ? 31 - c : c;
          float fax = FrP[srcT]      + FrP[32 + srcT];
          float fay = FiP[srcT]      + FiP[32 + srcT];
          float fbx = FrP[64 + srcU] + FrP[96 + srcU];
          float fby = FiP[64 + srcU] + FiP[96 + srcU];
          float gr = fax;
          float gi = cfT ? -fay : fay;
          if(!unpaired){
            gr += fbx;
            gi -= (cfU ? -fby : fby);
          }
          unsigned short hr = f2b(gr); float lr = gr - b2f(hr);
          unsigned short hi2 = f2b(gi); float li = gi - b2f(hi2);
          int hhc = c >> 4, cl = c & 15;
          int kk1 = k >> 5, q1 = (k >> 3) & 3, e1 = k & 7;
          size_t fb2 = (size_t)(b * 2 + hhc) * 18;
          size_t off = (size_t)(q1 * 16 + cl) * 8 + e1;
          ghif[(fb2 + kk1) * 512 + off]     = hr;
          ghif[(fb2 + 9 + kk1) * 512 + off] = hi2;
          glof[(fb2 + kk1) * 512 + off]     = f2b(lr);
          glof[(fb2 + 9 + kk1) * 512 + off] = f2b(li);
        }
        __syncthreads();
      }
    }
    gbar(bar, B);

    // ---- I: inverse transform + conv fold (verbatim R9 k_inv body) ----
    {
      for(int v = B; v < 1024; v += GRID){
        int bx = v & 255, b = v >> 8;
        const int lane = tid & 63, w = tid >> 6;
        const int tl = w >> 1;
        const int hh = w & 1;
        const int row = lane & 15, q = lane >> 4;
        const int t16 = bx * 2 + tl;
        const ushort_t* vb = VTF + ((size_t)(b * 512 + t16) * 18) * 512 + lane * 8;
        const ushort_t* gh = ghif + ((size_t)(b * 2 + hh) * 18) * 512 + lane * 8;
        const ushort_t* gl = glof + ((size_t)(b * 2 + hh) * 18) * 512 + lane * 8;
        floatx4 ah = {0.f,0.f,0.f,0.f}, al = {0.f,0.f,0.f,0.f};
        #pragma unroll
        for(int kk = 0; kk < 18; ++kk){
          short8 Bv = *(const short8*)(vb + (size_t)kk * 512);
          short8 Ah = *(const short8*)(gh + (size_t)kk * 512);
          short8 Al = *(const short8*)(gl + (size_t)kk * 512);
          ah = __builtin_amdgcn_mfma_f32_16x16x32_bf16(Ah, Bv, ah, 0, 0, 0);
          al = __builtin_amdgcn_mfma_f32_16x16x32_bf16(Al, Bv, al, 0, 0, 0);
        }
        {
          short8 Whi = *(const short8*)(WA + ((size_t)((l * 2 + 0) * 2 + hh)) * 512 + lane * 8);
          short8 Wlo = *(const short8*)(WA + ((size_t)((l * 2 + 1) * 2 + hh)) * 512 + lane * 8);
          short8 Bhi = *(const short8*)(hciH + ((size_t)(b * 512 + t16)) * 512 + lane * 8);
          short8 Blo = *(const short8*)(hciL + ((size_t)(b * 512 + t16)) * 512 + lane * 8);
          ah = __builtin_amdgcn_mfma_f32_16x16x32_bf16(Whi, Bhi, ah, 0, 0, 0);
          al = __builtin_amdgcn_mfma_f32_16x16x32_bf16(Wlo, Bhi, al, 0, 0, 0);
          ah = __builtin_amdgcn_mfma_f32_16x16x32_bf16(Whi, Blo, ah, 0, 0, 0);
        }
        floatx4 accF = ah + al;
        const float sc = 2.0f / 8192.0f;
        float cb[4];
        #pragma unroll
        for(int r = 0; r < 4; ++r) cb[r] = A.convb[l * 32 + hh * 16 + q * 4 + r];
        if(l < 3){
          const int n = bx * 32 + tl * 16 + row;
          const int g2 = n >> 5, qb = (n >> 3) & 3, e2 = n & 7;
          #pragma unroll
          for(int r = 0; r < 4; ++r){
            int c = hh * 16 + q * 4 + r;
            float vv = gelu_f(accF[r] * sc + cb[r]);
            ushort_t hi = f2b(vv), lo = f2b(vv - b2f(hi));
            hbBo[(((size_t)(b * 2 + hh) * 256 + g2) * 512) + (qb * 16 + (q * 4 + r)) * 8 + e2] = hi;
            size_t ca = ((size_t)(b * 512 + t16)) * 512 + ((c >> 3) * 16 + row) * 8 + (c & 7);
            hcoH[ca] = hi; hcoL[ca] = lo;
          }
        } else {
          ushort_t* hHi = (ushort_t*)SMEM;          // [32][36]
          ushort_t* hLo = hHi + 1152;
          float*    prt = (float*)(SMEM + 4608);    // [2][32]
          {
            ushort_t H[4], L[4];
            #pragma unroll
            for(int r = 0; r < 4; ++r){
              float vv = accF[r] * sc + cb[r];
              H[r] = f2b(vv); L[r] = f2b(vv - b2f(H[r]));
            }
            uint2 uu;
            uu.x = (unsigned)H[0] | ((unsigned)H[1] << 16);
            uu.y = (unsigned)H[2] | ((unsigned)H[3] << 16);
            *(uint2*)&hHi[(tl * 16 + row) * 36 + hh * 16 + q * 4] = uu;
            uu.x = (unsigned)L[0] | ((unsigned)L[1] << 16);
            uu.y = (unsigned)L[2] | ((unsigned)L[3] << 16);
            *(uint2*)&hLo[(tl * 16 + row) * 36 + hh * 16 + q * 4] = uu;
          }
          __syncthreads();
          const int cl = row;
          short8 Ahi = *(const short8*)&hHi[(tl * 16 + cl) * 36 + q * 8];
          short8 Alo = *(const short8*)&hLo[(tl * 16 + cl) * 36 + q * 8];
          float S0 = 0.f, S1 = 0.f, S2 = 0.f, S3 = 0.f;
          #pragma unroll
          for(int jt2 = 0; jt2 < 4; ++jt2){
            int jt = hh * 4 + jt2;
            short8 Bhi = *(const short8*)(WB + (jt * 64 + lane) * 8);
            short8 Blo = *(const short8*)(WB + 4096 + (jt * 64 + lane) * 8);
            floatx4 acc = {0.f, 0.f, 0.f, 0.f};
            acc = __builtin_amdgcn_mfma_f32_16x16x32_bf16(Ahi, Bhi, acc, 0, 0, 0);
            acc = __builtin_amdgcn_mfma_f32_16x16x32_bf16(Alo, Bhi, acc, 0, 0, 0);
            acc = __builtin_amdgcn_mfma_f32_16x16x32_bf16(Ahi, Blo, acc, 0, 0, 0);
            float bv = A.fc1b[jt * 16 + cl], wv2 = A.fc2w[jt * 16 + cl];
            S0 = fmaf(gelu_f(acc[0] + bv), wv2, S0);
            S1 = fmaf(gelu_f(acc[1] + bv), wv2, S1);
            S2 = fmaf(gelu_f(acc[2] + bv), wv2, S2);
            S3 = fmaf(gelu_f(acc[3] + bv), wv2, S3);
          }
          #pragma unroll
          for(int off = 8; off; off >>= 1){
            S0 += __shfl_xor(S0, off, 16);
            S1 += __shfl_xor(S1, off, 16);
            S2 += __shfl_xor(S2, off, 16);
            S3 += __shfl_xor(S3, off, 16);
          }
          if(cl == 0){
            int pb = tl * 16 + q * 4;
            prt[hh * 32 + pb + 0] = S0;
            prt[hh * 32 + pb + 1] = S1;
            prt[hh * 32 + pb + 2] = S2;
            prt[hh * 32 + pb + 3] = S3;
          }
          __syncthreads();
          if(tid < 32)
            A.out[(size_t)b * NN + bx * 32 + tid] = prt[tid] + prt[32 + tid] + A.fc2b[0];
          __syncthreads();
        }
      }
    }
    if(l < 3) gbar(bar, B);
  }
}

// ---------- launch ----------
extern "C" void kernel_launch(void* const* d_in, const int* in_sizes, int n_in,
                              void* d_out, int out_size, void* d_ws, size_t ws_size,
                              hipStream_t stream)
{
  MArgs ma;
  ma.x     = (const float*)d_in[0];
  ma.fc0w  = (const float*)d_in[1];
  ma.fc0b  = (const float*)d_in[2];
  ma.spec  = (const float*)d_in[3];
  ma.convw = (const float*)d_in[4];
  ma.convb = (const float*)d_in[5];
  ma.fc1w  = (const float*)d_in[6];
  ma.fc1b  = (const float*)d_in[7];
  ma.fc2w  = (const float*)d_in[8];
  ma.fc2b  = (const float*)d_in[9];
  ma.out   = (float*)d_out;
  ma.ws    = (char*)d_ws;
  // zero the barrier region (sub counters + root + gen), stream-ordered
  hipMemsetAsync((char*)d_ws + OFF_BAR, 0, 2048, stream);
  hipLaunchKernelGGL(k_mega, dim3(GRID), dim3(256), 0, stream, ma);
  (void)in_sizes; (void)n_in; (void)out_size; (void)ws_size;
}

// Round 12
// 307.658 us; speedup vs baseline: 4.5137x; 3.5142x over previous
//
#include <hip/hip_runtime.h>
#include <cmath>

#define NB 4
#define NN 8192
#define CH 32

typedef short short8 __attribute__((ext_vector_type(8)));
typedef float floatx4 __attribute__((ext_vector_type(4)));
typedef unsigned short ushort_t;

// ---------- helpers ----------
__device__ __forceinline__ unsigned short f2b(float f){
  unsigned u = __float_as_uint(f);
  u = u + 0x7FFFu + ((u >> 16) & 1u);   // RNE
  return (unsigned short)(u >> 16);
}
__device__ __forceinline__ float b2f(unsigned short h){
  return __uint_as_float(((unsigned)h) << 16);
}
__device__ __forceinline__ float gelu_f(float v){
  return 0.5f * v * (1.0f + erff(v * 0.70710678118654752440f));
}
__device__ __forceinline__ int repk(int t){
  int j = t / 24, i = t - j * 24;
  if(j == 0)  return (i <= 12) ? i : -1;
  if(j <= 11) return 13 + (j - 1) * 24 + i;
  return (i == 12) ? 277 + (j - 12) : -1;
}
__device__ __forceinline__ int partner(int t){
  int j = t / 24, i = t - j * 24;
  return ((23 - j) % 23) * 24 + ((24 - i) % 24);
}
__device__ __forceinline__ int repT(int k){
  if(k < 13) return k;
  if(k < 277){ int m = k - 13; return (m / 24 + 1) * 24 + (m % 24); }
  return (k - 277 + 12) * 24 + 12;
}

// ---------- fused: spec_w reorder + minmax partials + fc1_w/conv_w fragment pre-split ----------
__global__ __launch_bounds__(256) void k_pre(const float* __restrict__ spec,
    float2* __restrict__ wt, const float* __restrict__ x, float4* __restrict__ pmm,
    const float* __restrict__ fc1w, ushort_t* __restrict__ WB,
    const float* __restrict__ convw, ushort_t* __restrict__ WA)
{
  const int tid = threadIdx.x;
  if(blockIdx.x < 128){
    int g = blockIdx.x * 256 + tid;           // 32768 threads
    float a = x[(size_t)g * 2], b = x[(size_t)g * 2 + 1];
    float mn0 = a, mx0 = a, mn1 = b, mx1 = b;
    for(int off = 32; off > 0; off >>= 1){
      mn0 = fminf(mn0, __shfl_down(mn0, off));
      mx0 = fmaxf(mx0, __shfl_down(mx0, off));
      mn1 = fminf(mn1, __shfl_down(mn1, off));
      mx1 = fmaxf(mx1, __shfl_down(mx1, off));
    }
    __shared__ float4 wp[4];
    if((tid & 63) == 0) wp[tid >> 6] = make_float4(mn0, mn1, mx0, mx1);
    __syncthreads();
    if(tid == 0){
      float4 r = wp[0];
      for(int i2 = 1; i2 < 4; ++i2){
        float4 v = wp[i2];
        r.x = fminf(r.x, v.x); r.y = fminf(r.y, v.y);
        r.z = fmaxf(r.z, v.z); r.w = fmaxf(r.w, v.w);
      }
      pmm[blockIdx.x] = r;
    }
  } else if(blockIdx.x < 4736){
    int g = (blockIdx.x - 128) * 256 + tid;   // 1,179,648
    int o  = g & 31;
    int i  = (g >> 5) & 31;
    int rest = g >> 10;
    int pq = rest % 144;
    int ls = rest / 144;                      // l*2+sel
    wt[g] = ((const float2*)spec)[(((size_t)(ls * 32 + i) * 32 + o) * 144 + pq)];
  } else {
    // fc1_w [32][128] -> bf16 hi/lo MFMA B-fragments, 8 jj-tiles.
    for(int s = tid; s < 512; s += 256){
      int jt = s >> 6, l = s & 63;
      int c = l & 15, qq = l >> 4;
      #pragma unroll
      for(int e = 0; e < 8; ++e){
        float wv = fc1w[(qq * 8 + e) * 128 + jt * 16 + c];
        ushort_t hi = f2b(wv);
        WB[(jt * 64 + l) * 8 + e] = hi;
        WB[4096 + (jt * 64 + l) * 8 + e] = f2b(wv - b2f(hi));
      }
    }
    // conv_w [4][32][32] * 4096 -> A-fragments, hi/lo limbs, 2 ch-halves.
    for(int s = tid; s < 8192; s += 256){
      int l2   = s >> 11;
      int rem  = s & 2047;
      int limb = rem >> 10;
      int rem2 = rem & 1023;
      int half = rem2 >> 9;
      int le   = rem2 & 511;
      int lane = le >> 3, e = le & 7;
      int c = half * 16 + (lane & 15);
      int i = (lane >> 4) * 8 + e;
      float wv = convw[((size_t)l2 * 32 + c) * 32 + i] * 4096.0f;
      ushort_t hi = f2b(wv);
      WA[s] = limb ? f2b(wv - b2f(hi)) : hi;
    }
  }
}

// ---------- build V in MFMA-fragment layouts + fc0 (verbatim R9) ----------
__global__ __launch_bounds__(256) void k_vbuild(const float* __restrict__ x,
    const float4* __restrict__ pmm, const float* __restrict__ fw,
    const float* __restrict__ fb, ushort_t* __restrict__ AF, ushort_t* __restrict__ VTF,
    ushort_t* __restrict__ hbB, ushort_t* __restrict__ hbChi, ushort_t* __restrict__ hbClo)
{
  __shared__ ushort_t lds1[32 * 584];
  __shared__ float4 mmv;
  const int tid = threadIdx.x;
  if(tid < 64){
    float4 a = pmm[tid], c = pmm[tid + 64];
    float mn0 = fminf(a.x, c.x), mn1 = fminf(a.y, c.y);
    float mx0 = fmaxf(a.z, c.z), mx1 = fmaxf(a.w, c.w);
    for(int off = 32; off > 0; off >>= 1){
      mn0 = fminf(mn0, __shfl_down(mn0, off));
      mn1 = fminf(mn1, __shfl_down(mn1, off));
      mx0 = fmaxf(mx0, __shfl_down(mx0, off));
      mx1 = fmaxf(mx1, __shfl_down(mx1, off));
    }
    if(tid == 0) mmv = make_float4(mn0, mn1, mx0, mx1);
  }
  __syncthreads();
  const int nl = tid & 31, part = tid >> 5;
  const int b = blockIdx.x >> 8;
  const int nblk = blockIdx.x & 255;
  const int n = nblk * 32 + nl;
  float mn0 = mmv.x, mn1 = mmv.y, mx0 = mmv.z, mx1 = mmv.w;
  float x0 = x[(size_t)(b * NN + n) * 2]     - mn0;
  float x1 = x[(size_t)(b * NN + n) * 2 + 1] - mn1;
  float sp = x0 * (6.28f / (mx0 - mn0));
  float sq = x1 * (6.28f / (mx1 - mn1));
  float cx, sx, cy, sy;
  sincosf(sp, &sx, &cx);
  sincosf(sq, &sy, &cy);
  int j0 = part * 3;
  int j1 = (j0 + 3 < 23) ? j0 + 3 : 23;
  float ky0 = (j0 < 12) ? (float)j0 : (float)(j0 - 23);
  float cb, sb;
  sincosf(ky0 * sq, &sb, &cb);
  for(int j = j0; j < j1; ++j){
    float ca = 1.0f, sa = 0.0f;   // kx = 0
    #pragma unroll
    for(int i = 0; i < 24; ++i){
      float vr = ca * cb - sa * sb;
      float vi = -(sa * cb + ca * sb);
      int t = j * 24 + i;
      int k = repk(t);
      if(k >= 0){
        lds1[nl * 584 + k]       = f2b(vr);
        lds1[nl * 584 + 288 + k] = f2b(vi);
      }
      float cn = ca * cx - sa * sx;
      float sn = sa * cx + ca * sx;
      if(i == 11) sn = -sn;
      ca = cn; sa = sn;
    }
    float cbn = cb * cy - sb * sy;
    float sbn = sb * cy + cb * sy;
    cb = cbn; sb = sbn;
  }
  __syncthreads();
  #pragma unroll
  for(int r = 0; r < 9; ++r){
    int c = tid + 256 * r;
    int t16 = c / 1152;
    int c2 = c - t16 * 1152;
    int kk = c2 >> 6;
    int rem = c2 & 63;
    int q = rem >> 4, n15 = rem & 15;
    short8 v = *(const short8*)(lds1 + (t16 * 16 + n15) * 584 + kk * 32 + q * 8);
    *(short8*)(VTF + ((size_t)((b * 512 + nblk * 2 + t16) * 18 + kk)) * 512
               + (q * 16 + n15) * 8) = v;
  }
  #pragma unroll
  for(int r = 0; r < 9; ++r){
    int c = tid + 256 * r;
    int st = c >> 6;
    int rem = c & 63;
    int q = rem >> 4, srow = rem & 15;
    int sg = st * 16 + srow;
    int s = (sg < 288) ? sg : sg - 288;
    int sinh_ = (sg >= 288);
    int p2 = s / 12, qq = s - p2 * 12;
    int t = p2 * 23 + qq;
    int k = repk(t);
    unsigned short flip = 0;
    if(k < 0){ k = repk(partner(t)); if(sinh_) flip = 0x8000; }
    int col = sinh_ ? 288 + k : k;
    ushort_t tmp[8];
    #pragma unroll
    for(int e = 0; e < 8; ++e)
      tmp[e] = lds1[(q * 8 + e) * 584 + col] ^ flip;
    *(short8*)(AF + ((size_t)((b * 36 + st) * 256 + nblk)) * 512
               + (q * 16 + srow) * 8) = *(short8*)tmp;
  }
  #pragma unroll
  for(int rr = 0; rr < 4; ++rr){
    int c2 = part + rr * 8;
    float v = fb[c2] + x0 * fw[c2] + x1 * fw[32 + c2];
    ushort_t hi = f2b(v), lo = f2b(v - b2f(hi));
    int half = c2 >> 4, cl = c2 & 15;
    hbB[(((size_t)(b * 2 + half) * 256 + nblk) * 512) + ((nl >> 3) * 16 + cl) * 8 + (nl & 7)] = hi;
    size_t ca = ((size_t)(b * 512 + nblk * 2 + (nl >> 4))) * 512
              + ((c2 >> 3) * 16 + (nl & 15)) * 8 + (c2 & 7);
    hbChi[ca] = hi; hbClo[ca] = lo;
  }
}

// ---------- FUSED forward transform + mix + fold -> ghif/glof ----------
// One block per 4 reps (= 16 xp rows = one MFMA A-tile), grid (72,NB) x 512thr.
// Each lane GATHERS its A-row fragment from AF (row -> (st,srow), 16B loads,
// L2/L3-served); B = hbB fragments (contiguous). 8 waves split K (g=32 each),
// LDS-reduce -> X[16 rows][32 ch], then mix (8 waves: rep x m) + fold (4 waves)
// verbatim from the proven k_mixg, emitting ghif/glof A-fragments directly.
// Removes the xp buffer and one dispatch per layer (no grid-wide sync needed:
// a block computes exactly the rows its reps consume).
__global__ __launch_bounds__(512, 2) void k_fm(const ushort_t* __restrict__ AF,
    const ushort_t* __restrict__ hbB, const float2* __restrict__ wt,
    ushort_t* __restrict__ ghif, ushort_t* __restrict__ glof, int layer)
{
  const int rq = blockIdx.x;      // rep quad: reps rq*4 .. rq*4+3
  const int b  = blockIdx.y;
  const int tid = threadIdx.x;
  const int wv = tid >> 6, lane = tid & 63;
  const int cl = lane & 15, q = lane >> 4;
  __shared__ float red[8][16][32];            // 16 KB wave partials
  __shared__ float X[16][33];                 // reduced rows (padded)
  __shared__ float Fr[4][2][32], Fi[4][2][32];
  // --- per-lane A-row gather address: tile row = cl -> (rep, slot) -> sg ---
  {
    int r4 = cl >> 2, slot = cl & 3;
    int k0 = rq * 4 + r4;
    int t0 = repT(k0);
    int u0 = partner(t0);
    int idxT0 = (t0 < 288) ? t0 : 575 - t0;
    int idxU0 = (u0 < 288) ? u0 : 575 - u0;
    int sg = (slot == 0) ? idxT0 : (slot == 1) ? 288 + idxT0
           : (slot == 2) ? idxU0 : 288 + idxU0;
    int st = sg >> 4, srow = sg & 15;
    const size_t abase = ((size_t)(b * 36 + st) * 256) * 512 + (q * 16 + srow) * 8;
    const size_t hB0 = ((size_t)(b * 2 + 0) * 256) * 512 + (size_t)lane * 8;
    const size_t hB1 = ((size_t)(b * 2 + 1) * 256) * 512 + (size_t)lane * 8;
    floatx4 a0 = {0.f,0.f,0.f,0.f}, a1 = {0.f,0.f,0.f,0.f};
    #pragma unroll 4
    for(int gi = 0; gi < 32; ++gi){
      int g = wv * 32 + gi;
      short8 Av = *(const short8*)(AF + abase + (size_t)g * 512);
      short8 B0 = *(const short8*)(hbB + hB0 + (size_t)g * 512);
      short8 B1 = *(const short8*)(hbB + hB1 + (size_t)g * 512);
      a0 = __builtin_amdgcn_mfma_f32_16x16x32_bf16(Av, B0, a0, 0, 0, 0);
      a1 = __builtin_amdgcn_mfma_f32_16x16x32_bf16(Av, B1, a1, 0, 0, 0);
    }
    #pragma unroll
    for(int r = 0; r < 4; ++r){
      red[wv][q * 4 + r][cl]      = a0[r];
      red[wv][q * 4 + r][16 + cl] = a1[r];
    }
  }
  __syncthreads();
  // --- reduce 8 wave partials -> X[16][32] (fixed order w=0..7) ---
  {
    int tr = tid >> 5, o = tid & 31;
    float s = red[0][tr][o];
    #pragma unroll
    for(int w = 1; w < 8; ++w) s += red[w][tr][o];
    X[tr][o] = s;
  }
  __syncthreads();
  // --- phase B: wave (r4 = wv>>1, m = wv&1), lanes 0..31 do the 32-i mix ---
  {
    int r4b = wv >> 1, m = wv & 1;
    int kb = rq * 4 + r4b;
    int tb = repT(kb);
    int ub = partner(tb);
    int idx = m ? ((ub < 288) ? ub : 575 - ub) : ((tb < 288) ? tb : 575 - tb);
    int p2 = idx / 12, qq = idx - p2 * 12;
    int sel = (p2 < 12) ? 0 : 1;
    int pq = (p2 % 12) * 12 + qq;
    const float2* wb = wt + ((size_t)((layer * 2 + sel) * 144 + pq)) * 1024;
    if(lane < 32){
      const int o = lane;
      const int rc = r4b * 4 + 2 * m, rs = rc + 1;
      float fr = 0.f, fi = 0.f;
      #pragma unroll
      for(int ii = 0; ii < 32; ++ii){
        float xr = X[rc][ii], xi = X[rs][ii];
        float2 wvv = wb[ii * 32 + o];
        fr += xr * wvv.x - xi * wvv.y;
        fi += xr * wvv.y + xi * wvv.x;
      }
      Fr[r4b][m][o] = fr; Fi[r4b][m][o] = fi;
    }
  }
  __syncthreads();
  // --- phase C: wave r4 (wv<4), lanes 0..31: fold + emit (verbatim mapping) ---
  if(wv < 4 && lane < 32){
    const int k = rq * 4 + wv;
    const int t = repT(k);
    const int i = t - (t / 24) * 24;
    const int u = partner(t);
    const bool unpaired = (i == 12) || (u == t);
    const bool cfT = (t >= 288);
    const bool cfU = (u >= 288);
    const int c = lane;
    const int srcT = cfT ? 31 - c : c;
    const int srcU = cfU ? 31 - c : c;
    float fax = Fr[wv][0][srcT];
    float fay = Fi[wv][0][srcT];
    float fbx = Fr[wv][1][srcU];
    float fby = Fi[wv][1][srcU];
    float gr = fax;
    float gi = cfT ? -fay : fay;
    if(!unpaired){
      gr += fbx;
      gi -= (cfU ? -fby : fby);
    }
    unsigned short hr = f2b(gr); float lr = gr - b2f(hr);
    unsigned short hi2 = f2b(gi); float li = gi - b2f(hi2);
    int hhc = c >> 4, clc = c & 15;
    int kk1 = k >> 5, q1 = (k >> 3) & 3, e1 = k & 7;
    size_t fb2 = (size_t)(b * 2 + hhc) * 18;
    size_t off = (size_t)(q1 * 16 + clc) * 8 + e1;
    ghif[(fb2 + kk1) * 512 + off]     = hr;
    ghif[(fb2 + 9 + kk1) * 512 + off] = hi2;
    glof[(fb2 + kk1) * 512 + off]     = f2b(lr);
    glof[(fb2 + 9 + kk1) * 512 + off] = f2b(li);
  }
}

// ---------- inverse transform + MFMA-folded conv (+gelu | +MFMA fc1/fc2) — verbatim R9 ----------
template<int LAST>
__global__ __launch_bounds__(256, 6) void k_inv(const ushort_t* __restrict__ VTF,
    const ushort_t* __restrict__ ghif, const ushort_t* __restrict__ glof,
    const float* __restrict__ cbias, int layer,
    const ushort_t* __restrict__ hbCi_hi, const ushort_t* __restrict__ hbCi_lo,
    ushort_t* __restrict__ hbBo, ushort_t* __restrict__ hbCo_hi,
    ushort_t* __restrict__ hbCo_lo,
    const float* __restrict__ b1, const float* __restrict__ w2,
    const float* __restrict__ b2, float* __restrict__ out,
    const ushort_t* __restrict__ WBg, const ushort_t* __restrict__ WA)
{
  const int tid = threadIdx.x;
  const int b = blockIdx.y;
  const int bx = blockIdx.x;
  const int lane = tid & 63;
  const int w = tid >> 6;
  const int tl = w >> 1;
  const int hh = w & 1;
  const int row = lane & 15, q = lane >> 4;
  const int t16 = bx * 2 + tl;
  const ushort_t* vb = VTF + ((size_t)(b * 512 + t16) * 18) * 512 + lane * 8;
  const ushort_t* gh = ghif + ((size_t)(b * 2 + hh) * 18) * 512 + lane * 8;
  const ushort_t* gl = glof + ((size_t)(b * 2 + hh) * 18) * 512 + lane * 8;
  floatx4 ah = {0.f,0.f,0.f,0.f}, al = {0.f,0.f,0.f,0.f};
  #pragma unroll
  for(int kk = 0; kk < 18; ++kk){
    short8 Bv = *(const short8*)(vb + (size_t)kk * 512);
    short8 Ah = *(const short8*)(gh + (size_t)kk * 512);
    short8 Al = *(const short8*)(gl + (size_t)kk * 512);
    ah = __builtin_amdgcn_mfma_f32_16x16x32_bf16(Ah, Bv, ah, 0, 0, 0);
    al = __builtin_amdgcn_mfma_f32_16x16x32_bf16(Al, Bv, al, 0, 0, 0);
  }
  {
    short8 Whi = *(const short8*)(WA + ((size_t)((layer * 2 + 0) * 2 + hh)) * 512 + lane * 8);
    short8 Wlo = *(const short8*)(WA + ((size_t)((layer * 2 + 1) * 2 + hh)) * 512 + lane * 8);
    short8 Bhi = *(const short8*)(hbCi_hi + ((size_t)(b * 512 + t16)) * 512 + lane * 8);
    short8 Blo = *(const short8*)(hbCi_lo + ((size_t)(b * 512 + t16)) * 512 + lane * 8);
    ah = __builtin_amdgcn_mfma_f32_16x16x32_bf16(Whi, Bhi, ah, 0, 0, 0);
    al = __builtin_amdgcn_mfma_f32_16x16x32_bf16(Wlo, Bhi, al, 0, 0, 0);
    ah = __builtin_amdgcn_mfma_f32_16x16x32_bf16(Whi, Blo, ah, 0, 0, 0);
  }
  floatx4 accF = ah + al;
  const float sc = 2.0f / 8192.0f;
  float cb[4];
  #pragma unroll
  for(int r = 0; r < 4; ++r) cb[r] = cbias[layer * 32 + hh * 16 + q * 4 + r];
  if constexpr(!LAST){
    const int n = bx * 32 + tl * 16 + row;
    const int g2 = n >> 5, qb = (n >> 3) & 3, e2 = n & 7;
    #pragma unroll
    for(int r = 0; r < 4; ++r){
      int c = hh * 16 + q * 4 + r;
      float v = gelu_f(accF[r] * sc + cb[r]);
      ushort_t hi = f2b(v), lo = f2b(v - b2f(hi));
      hbBo[(((size_t)(b * 2 + hh) * 256 + g2) * 512) + (qb * 16 + (q * 4 + r)) * 8 + e2] = hi;
      size_t ca = ((size_t)(b * 512 + t16)) * 512 + ((c >> 3) * 16 + row) * 8 + (c & 7);
      hbCo_hi[ca] = hi; hbCo_lo[ca] = lo;
    }
  } else {
    __shared__ ushort_t hHi[32][36];
    __shared__ ushort_t hLo[32][36];
    __shared__ float part[2][32];
    {
      ushort_t H[4], L[4];
      #pragma unroll
      for(int r = 0; r < 4; ++r){
        float v = accF[r] * sc + cb[r];
        H[r] = f2b(v); L[r] = f2b(v - b2f(H[r]));
      }
      uint2 uu;
      uu.x = (unsigned)H[0] | ((unsigned)H[1] << 16);
      uu.y = (unsigned)H[2] | ((unsigned)H[3] << 16);
      *(uint2*)&hHi[tl * 16 + row][hh * 16 + q * 4] = uu;
      uu.x = (unsigned)L[0] | ((unsigned)L[1] << 16);
      uu.y = (unsigned)L[2] | ((unsigned)L[3] << 16);
      *(uint2*)&hLo[tl * 16 + row][hh * 16 + q * 4] = uu;
    }
    __syncthreads();
    const int cl = row;
    short8 Ahi = *(const short8*)&hHi[tl * 16 + cl][q * 8];
    short8 Alo = *(const short8*)&hLo[tl * 16 + cl][q * 8];
    float S0 = 0.f, S1 = 0.f, S2 = 0.f, S3 = 0.f;
    #pragma unroll
    for(int jt2 = 0; jt2 < 4; ++jt2){
      int jt = hh * 4 + jt2;
      short8 Bhi = *(const short8*)(WBg + (jt * 64 + lane) * 8);
      short8 Blo = *(const short8*)(WBg + 4096 + (jt * 64 + lane) * 8);
      floatx4 acc = {0.f, 0.f, 0.f, 0.f};
      acc = __builtin_amdgcn_mfma_f32_16x16x32_bf16(Ahi, Bhi, acc, 0, 0, 0);
      acc = __builtin_amdgcn_mfma_f32_16x16x32_bf16(Alo, Bhi, acc, 0, 0, 0);
      acc = __builtin_amdgcn_mfma_f32_16x16x32_bf16(Ahi, Blo, acc, 0, 0, 0);
      float bv = b1[jt * 16 + cl], wv = w2[jt * 16 + cl];
      S0 = fmaf(gelu_f(acc[0] + bv), wv, S0);
      S1 = fmaf(gelu_f(acc[1] + bv), wv, S1);
      S2 = fmaf(gelu_f(acc[2] + bv), wv, S2);
      S3 = fmaf(gelu_f(acc[3] + bv), wv, S3);
    }
    #pragma unroll
    for(int off = 8; off; off >>= 1){
      S0 += __shfl_xor(S0, off, 16);
      S1 += __shfl_xor(S1, off, 16);
      S2 += __shfl_xor(S2, off, 16);
      S3 += __shfl_xor(S3, off, 16);
    }
    if(cl == 0){
      int pb = tl * 16 + q * 4;
      part[hh][pb + 0] = S0;
      part[hh][pb + 1] = S1;
      part[hh][pb + 2] = S2;
      part[hh][pb + 3] = S3;
    }
    __syncthreads();
    if(tid < 32)
      out[(size_t)b * NN + bx * 32 + tid] = part[0][tid] + part[1][tid] + b2[0];
  }
}

// ---------- launch (10 dispatches: pre, vbuild, 4 x (fm + inv)) ----------
extern "C" void kernel_launch(void* const* d_in, const int* in_sizes, int n_in,
                              void* d_out, int out_size, void* d_ws, size_t ws_size,
                              hipStream_t stream)
{
  const float* x      = (const float*)d_in[0];
  const float* fc0_w  = (const float*)d_in[1];
  const float* fc0_b  = (const float*)d_in[2];
  const float* spec_w = (const float*)d_in[3];
  const float* conv_w = (const float*)d_in[4];
  const float* conv_b = (const float*)d_in[5];
  const float* fc1_w  = (const float*)d_in[6];
  const float* fc1_b  = (const float*)d_in[7];
  const float* fc2_w  = (const float*)d_in[8];
  const float* fc2_b  = (const float*)d_in[9];
  float* out = (float*)d_out;

  char* w = (char*)d_ws;
  const size_t OFF_PMM  = 0;
  const size_t OFF_WT   = 4096;
  const size_t OFF_AF   = OFF_WT  + 9437184;
  const size_t OFF_VTF  = OFF_AF  + 37748736;
  const size_t OFF_HB0  = OFF_VTF + 37748736;   // hbB hi, ping
  const size_t OFF_HB1  = OFF_HB0 + 2097152;
  const size_t OFF_HC0  = OFF_HB1 + 2097152;    // hbC hi, ping
  const size_t OFF_HC1  = OFF_HC0 + 2097152;
  const size_t OFF_HL0  = OFF_HC1 + 2097152;    // hbC lo, ping
  const size_t OFF_HL1  = OFF_HL0 + 2097152;
  const size_t OFF_GHF  = OFF_HL1 + 2097152;
  const size_t OFF_GLO  = OFF_GHF + 147456;
  const size_t OFF_WB   = OFF_GLO + 147456;
  const size_t OFF_WA   = OFF_WB  + 16384;

  float4* pmm    = (float4*)(w + OFF_PMM);
  float2* wt     = (float2*)(w + OFF_WT);
  ushort_t* AF   = (ushort_t*)(w + OFF_AF);
  ushort_t* VTF  = (ushort_t*)(w + OFF_VTF);
  ushort_t* hbB[2]  = { (ushort_t*)(w + OFF_HB0), (ushort_t*)(w + OFF_HB1) };
  ushort_t* hbChi[2] = { (ushort_t*)(w + OFF_HC0), (ushort_t*)(w + OFF_HC1) };
  ushort_t* hbClo[2] = { (ushort_t*)(w + OFF_HL0), (ushort_t*)(w + OFF_HL1) };
  ushort_t* ghif = (ushort_t*)(w + OFF_GHF);
  ushort_t* glof = (ushort_t*)(w + OFF_GLO);
  ushort_t* WB   = (ushort_t*)(w + OFF_WB);
  ushort_t* WA   = (ushort_t*)(w + OFF_WA);

  hipLaunchKernelGGL(k_pre, dim3(4737), dim3(256), 0, stream, spec_w, wt, x, pmm,
                     fc1_w, WB, conv_w, WA);
  hipLaunchKernelGGL(k_vbuild, dim3(1024), dim3(256), 0, stream, x, pmm,
                     fc0_w, fc0_b, AF, VTF, hbB[0], hbChi[0], hbClo[0]);

  for(int l = 0; l < 4; ++l){
    int in = l & 1, outb = 1 - in;
    hipLaunchKernelGGL(k_fm, dim3(72, NB), dim3(512), 0, stream, AF, hbB[in], wt,
                       ghif, glof, l);
    if(l < 3)
      hipLaunchKernelGGL(k_inv<0>, dim3(256, NB), dim3(256), 0, stream, VTF, ghif, glof,
                         conv_b, l, hbChi[in], hbClo[in],
                         hbB[outb], hbChi[outb], hbClo[outb],
                         fc1_b, fc2_w, fc2_b, out, WB, WA);
    else
      hipLaunchKernelGGL(k_inv<1>, dim3(256, NB), dim3(256), 0, stream, VTF, ghif, glof,
                         conv_b, l, hbChi[in], hbClo[in],
                         hbB[outb], hbChi[outb], hbClo[outb],
                         fc1_b, fc2_w, fc2_b, out, WB, WA);
  }
  (void)in_sizes; (void)n_in; (void)out_size; (void)ws_size;
}

// Round 13
// 275.941 us; speedup vs baseline: 5.0325x; 1.1149x over previous
//
#include <hip/hip_runtime.h>
#include <cmath>

#define NB 4
#define NN 8192
#define CH 32

typedef short short8 __attribute__((ext_vector_type(8)));
typedef float floatx4 __attribute__((ext_vector_type(4)));
typedef unsigned short ushort_t;

// ---------- helpers ----------
__device__ __forceinline__ unsigned short f2b(float f){
  unsigned u = __float_as_uint(f);
  u = u + 0x7FFFu + ((u >> 16) & 1u);   // RNE
  return (unsigned short)(u >> 16);
}
__device__ __forceinline__ float b2f(unsigned short h){
  return __uint_as_float(((unsigned)h) << 16);
}
__device__ __forceinline__ float gelu_f(float v){
  return 0.5f * v * (1.0f + erff(v * 0.70710678118654752440f));
}
__device__ __forceinline__ int repk(int t){
  int j = t / 24, i = t - j * 24;
  if(j == 0)  return (i <= 12) ? i : -1;
  if(j <= 11) return 13 + (j - 1) * 24 + i;
  return (i == 12) ? 277 + (j - 12) : -1;
}
__device__ __forceinline__ int partner(int t){
  int j = t / 24, i = t - j * 24;
  return ((23 - j) % 23) * 24 + ((24 - i) % 24);
}
__device__ __forceinline__ int repT(int k){
  if(k < 13) return k;
  if(k < 277){ int m = k - 13; return (m / 24 + 1) * 24 + (m % 24); }
  return (k - 277 + 12) * 24 + 12;
}

// ---------- fused: spec_w reorder + minmax partials + fc1_w/conv_w fragment pre-split ----------
__global__ __launch_bounds__(256) void k_pre(const float* __restrict__ spec,
    float2* __restrict__ wt, const float* __restrict__ x, float4* __restrict__ pmm,
    const float* __restrict__ fc1w, ushort_t* __restrict__ WB,
    const float* __restrict__ convw, ushort_t* __restrict__ WA)
{
  const int tid = threadIdx.x;
  if(blockIdx.x < 128){
    int g = blockIdx.x * 256 + tid;           // 32768 threads
    float a = x[(size_t)g * 2], b = x[(size_t)g * 2 + 1];
    float mn0 = a, mx0 = a, mn1 = b, mx1 = b;
    for(int off = 32; off > 0; off >>= 1){
      mn0 = fminf(mn0, __shfl_down(mn0, off));
      mx0 = fmaxf(mx0, __shfl_down(mx0, off));
      mn1 = fminf(mn1, __shfl_down(mn1, off));
      mx1 = fmaxf(mx1, __shfl_down(mx1, off));
    }
    __shared__ float4 wp[4];
    if((tid & 63) == 0) wp[tid >> 6] = make_float4(mn0, mn1, mx0, mx1);
    __syncthreads();
    if(tid == 0){
      float4 r = wp[0];
      for(int i2 = 1; i2 < 4; ++i2){
        float4 v = wp[i2];
        r.x = fminf(r.x, v.x); r.y = fminf(r.y, v.y);
        r.z = fmaxf(r.z, v.z); r.w = fmaxf(r.w, v.w);
      }
      pmm[blockIdx.x] = r;
    }
  } else if(blockIdx.x < 4736){
    int g = (blockIdx.x - 128) * 256 + tid;   // 1,179,648
    int o  = g & 31;
    int i  = (g >> 5) & 31;
    int rest = g >> 10;
    int pq = rest % 144;
    int ls = rest / 144;                      // l*2+sel
    wt[g] = ((const float2*)spec)[(((size_t)(ls * 32 + i) * 32 + o) * 144 + pq)];
  } else {
    // fc1_w [32][128] -> bf16 hi/lo MFMA B-fragments, 8 jj-tiles.
    for(int s = tid; s < 512; s += 256){
      int jt = s >> 6, l = s & 63;
      int c = l & 15, qq = l >> 4;
      #pragma unroll
      for(int e = 0; e < 8; ++e){
        float wv = fc1w[(qq * 8 + e) * 128 + jt * 16 + c];
        ushort_t hi = f2b(wv);
        WB[(jt * 64 + l) * 8 + e] = hi;
        WB[4096 + (jt * 64 + l) * 8 + e] = f2b(wv - b2f(hi));
      }
    }
    // conv_w [4][32][32] * 4096 -> A-fragments, hi/lo limbs, 2 ch-halves.
    for(int s = tid; s < 8192; s += 256){
      int l2   = s >> 11;
      int rem  = s & 2047;
      int limb = rem >> 10;
      int rem2 = rem & 1023;
      int half = rem2 >> 9;
      int le   = rem2 & 511;
      int lane = le >> 3, e = le & 7;
      int c = half * 16 + (lane & 15);
      int i = (lane >> 4) * 8 + e;
      float wv = convw[((size_t)l2 * 32 + c) * 32 + i] * 4096.0f;
      ushort_t hi = f2b(wv);
      WA[s] = limb ? f2b(wv - b2f(hi)) : hi;
    }
  }
}

// ---------- build V in MFMA-fragment layouts + fc0 ----------
// AFR: forward A-operand, REP-GROUPED rows. [b][st'=72][ng=256][q=4][srow=16][e=8]
//      tile st' = rep-quad rq; srow = r4*4+slot maps to original V-row
//      sg(k=rq*4+r4, slot) = {idxT, 288+idxT, idxU, 288+idxU}. Rows duplicated
//      ~2x (75.5 MB) but contiguous for k_fm and L3-resident across layers.
// VTF: inverse B-operand.  [b][n16=512][kk=18][q=4][n15=16][e=8] shorts
// hbB: forward B-operand (n-contraction). [b][half][g=256][q][cl][e]
// hbC: conv B-operand (ch-contraction).   [b][t16=512][q][cl][e]  (hi and lo)
__global__ __launch_bounds__(256) void k_vbuild(const float* __restrict__ x,
    const float4* __restrict__ pmm, const float* __restrict__ fw,
    const float* __restrict__ fb, ushort_t* __restrict__ AFR, ushort_t* __restrict__ VTF,
    ushort_t* __restrict__ hbB, ushort_t* __restrict__ hbChi, ushort_t* __restrict__ hbClo)
{
  __shared__ ushort_t lds1[32 * 584];
  __shared__ float4 mmv;
  const int tid = threadIdx.x;
  if(tid < 64){
    float4 a = pmm[tid], c = pmm[tid + 64];
    float mn0 = fminf(a.x, c.x), mn1 = fminf(a.y, c.y);
    float mx0 = fmaxf(a.z, c.z), mx1 = fmaxf(a.w, c.w);
    for(int off = 32; off > 0; off >>= 1){
      mn0 = fminf(mn0, __shfl_down(mn0, off));
      mn1 = fminf(mn1, __shfl_down(mn1, off));
      mx0 = fmaxf(mx0, __shfl_down(mx0, off));
      mx1 = fmaxf(mx1, __shfl_down(mx1, off));
    }
    if(tid == 0) mmv = make_float4(mn0, mn1, mx0, mx1);
  }
  __syncthreads();
  const int nl = tid & 31, part = tid >> 5;
  const int b = blockIdx.x >> 8;
  const int nblk = blockIdx.x & 255;
  const int n = nblk * 32 + nl;
  float mn0 = mmv.x, mn1 = mmv.y, mx0 = mmv.z, mx1 = mmv.w;
  float x0 = x[(size_t)(b * NN + n) * 2]     - mn0;
  float x1 = x[(size_t)(b * NN + n) * 2 + 1] - mn1;
  float sp = x0 * (6.28f / (mx0 - mn0));
  float sq = x1 * (6.28f / (mx1 - mn1));
  float cx, sx, cy, sy;
  sincosf(sp, &sx, &cx);
  sincosf(sq, &sy, &cy);
  int j0 = part * 3;
  int j1 = (j0 + 3 < 23) ? j0 + 3 : 23;
  float ky0 = (j0 < 12) ? (float)j0 : (float)(j0 - 23);
  float cb, sb;
  sincosf(ky0 * sq, &sb, &cb);
  for(int j = j0; j < j1; ++j){
    float ca = 1.0f, sa = 0.0f;   // kx = 0
    #pragma unroll
    for(int i = 0; i < 24; ++i){
      float vr = ca * cb - sa * sb;
      float vi = -(sa * cb + ca * sb);
      int t = j * 24 + i;
      int k = repk(t);
      if(k >= 0){
        lds1[nl * 584 + k]       = f2b(vr);
        lds1[nl * 584 + 288 + k] = f2b(vi);
      }
      float cn = ca * cx - sa * sx;
      float sn = sa * cx + ca * sx;
      if(i == 11) sn = -sn;
      ca = cn; sa = sn;
    }
    float cbn = cb * cy - sb * sy;
    float sbn = sb * cy + cb * sy;
    cb = cbn; sb = sbn;
  }
  __syncthreads();
  // phase-1 emission: VTF (coalesced 16B/lane)
  #pragma unroll
  for(int r = 0; r < 9; ++r){
    int c = tid + 256 * r;
    int t16 = c / 1152;
    int c2 = c - t16 * 1152;
    int kk = c2 >> 6;
    int rem = c2 & 63;
    int q = rem >> 4, n15 = rem & 15;
    short8 v = *(const short8*)(lds1 + (t16 * 16 + n15) * 584 + kk * 32 + q * 8);
    *(short8*)(VTF + ((size_t)((b * 512 + nblk * 2 + t16) * 18 + kk)) * 512
               + (q * 16 + n15) * 8) = v;
  }
  // phase-2 emission: AFR (rep-grouped rows) via conjugate symmetry from LDS
  #pragma unroll
  for(int r = 0; r < 18; ++r){
    int c = tid + 256 * r;                  // [0,4608)
    int stp = c >> 6;                       // rep quad rq (0..71)
    int rem = c & 63;
    int q = rem >> 4, srow = rem & 15;
    int kr = stp * 4 + (srow >> 2);         // rep index
    int slot = srow & 3;
    int tr = repT(kr);
    int ur = partner(tr);
    int idxT = (tr < 288) ? tr : 575 - tr;
    int idxU = (ur < 288) ? ur : 575 - ur;
    int sg = (slot == 0) ? idxT : (slot == 1) ? 288 + idxT
           : (slot == 2) ? idxU : 288 + idxU;
    int s = (sg < 288) ? sg : sg - 288;
    int sinh_ = (sg >= 288);
    int p2 = s / 12, qq = s - p2 * 12;
    int t = p2 * 23 + qq;
    int k = repk(t);
    unsigned short flip = 0;
    if(k < 0){ k = repk(partner(t)); if(sinh_) flip = 0x8000; }
    int col = sinh_ ? 288 + k : k;
    ushort_t tmp[8];
    #pragma unroll
    for(int e = 0; e < 8; ++e)
      tmp[e] = lds1[(q * 8 + e) * 584 + col] ^ flip;
    *(short8*)(AFR + ((size_t)((b * 72 + stp) * 256 + nblk)) * 512
               + (q * 16 + srow) * 8) = *(short8*)tmp;
  }
  // fused fc0 -> hbB (hi) + hbC (hi/lo)
  #pragma unroll
  for(int rr = 0; rr < 4; ++rr){
    int c2 = part + rr * 8;
    float v = fb[c2] + x0 * fw[c2] + x1 * fw[32 + c2];
    ushort_t hi = f2b(v), lo = f2b(v - b2f(hi));
    int half = c2 >> 4, cl = c2 & 15;
    hbB[(((size_t)(b * 2 + half) * 256 + nblk) * 512) + ((nl >> 3) * 16 + cl) * 8 + (nl & 7)] = hi;
    size_t ca = ((size_t)(b * 512 + nblk * 2 + (nl >> 4))) * 512
              + ((c2 >> 3) * 16 + (nl & 15)) * 8 + (c2 & 7);
    hbChi[ca] = hi; hbClo[ca] = lo;
  }
}

// ---------- FUSED forward transform + mix + fold -> ghif/glof ----------
// One block per rep quad, grid (72,NB) x 512thr. A-tiles CONTIGUOUS from AFR
// (st' = rq): 1 KB/wave loads like the old k_fwd — no gather. 8 waves split K
// (g=32 each), LDS-reduce -> X[16][32], then mix + fold verbatim from the
// R12-proven k_fm (bit-exact), emitting ghif/glof A-fragments directly.
__global__ __launch_bounds__(512, 2) void k_fm(const ushort_t* __restrict__ AFR,
    const ushort_t* __restrict__ hbB, const float2* __restrict__ wt,
    ushort_t* __restrict__ ghif, ushort_t* __restrict__ glof, int layer)
{
  const int rq = blockIdx.x;      // rep quad: reps rq*4 .. rq*4+3
  const int b  = blockIdx.y;
  const int tid = threadIdx.x;
  const int wv = tid >> 6, lane = tid & 63;
  const int cl = lane & 15, q = lane >> 4;
  __shared__ float red[8][16][32];            // 16 KB wave partials
  __shared__ float X[16][33];                 // reduced rows (padded)
  __shared__ float Fr[4][2][32], Fi[4][2][32];
  // --- MFMA over contiguous AFR tile st' = rq ---
  {
    const size_t abase = ((size_t)(b * 72 + rq) * 256) * 512 + (q * 16 + cl) * 8;
    const size_t hB0 = ((size_t)(b * 2 + 0) * 256) * 512 + (size_t)lane * 8;
    const size_t hB1 = ((size_t)(b * 2 + 1) * 256) * 512 + (size_t)lane * 8;
    floatx4 a0 = {0.f,0.f,0.f,0.f}, a1 = {0.f,0.f,0.f,0.f};
    #pragma unroll 4
    for(int gi = 0; gi < 32; ++gi){
      int g = wv * 32 + gi;
      short8 Av = *(const short8*)(AFR + abase + (size_t)g * 512);
      short8 B0 = *(const short8*)(hbB + hB0 + (size_t)g * 512);
      short8 B1 = *(const short8*)(hbB + hB1 + (size_t)g * 512);
      a0 = __builtin_amdgcn_mfma_f32_16x16x32_bf16(Av, B0, a0, 0, 0, 0);
      a1 = __builtin_amdgcn_mfma_f32_16x16x32_bf16(Av, B1, a1, 0, 0, 0);
    }
    #pragma unroll
    for(int r = 0; r < 4; ++r){
      red[wv][q * 4 + r][cl]      = a0[r];
      red[wv][q * 4 + r][16 + cl] = a1[r];
    }
  }
  __syncthreads();
  // --- reduce 8 wave partials -> X[16][32] (fixed order w=0..7) ---
  {
    int tr = tid >> 5, o = tid & 31;
    float s = red[0][tr][o];
    #pragma unroll
    for(int w = 1; w < 8; ++w) s += red[w][tr][o];
    X[tr][o] = s;
  }
  __syncthreads();
  // --- phase B: wave (r4 = wv>>1, m = wv&1), lanes 0..31 do the 32-i mix ---
  {
    int r4b = wv >> 1, m = wv & 1;
    int kb = rq * 4 + r4b;
    int tb = repT(kb);
    int ub = partner(tb);
    int idx = m ? ((ub < 288) ? ub : 575 - ub) : ((tb < 288) ? tb : 575 - tb);
    int p2 = idx / 12, qq = idx - p2 * 12;
    int sel = (p2 < 12) ? 0 : 1;
    int pq = (p2 % 12) * 12 + qq;
    const float2* wb = wt + ((size_t)((layer * 2 + sel) * 144 + pq)) * 1024;
    if(lane < 32){
      const int o = lane;
      const int rc = r4b * 4 + 2 * m, rs = rc + 1;
      float fr = 0.f, fi = 0.f;
      #pragma unroll
      for(int ii = 0; ii < 32; ++ii){
        float xr = X[rc][ii], xi = X[rs][ii];
        float2 wvv = wb[ii * 32 + o];
        fr += xr * wvv.x - xi * wvv.y;
        fi += xr * wvv.y + xi * wvv.x;
      }
      Fr[r4b][m][o] = fr; Fi[r4b][m][o] = fi;
    }
  }
  __syncthreads();
  // --- phase C: wave r4 (wv<4), lanes 0..31: fold + emit (verbatim mapping) ---
  if(wv < 4 && lane < 32){
    const int k = rq * 4 + wv;
    const int t = repT(k);
    const int i = t - (t / 24) * 24;
    const int u = partner(t);
    const bool unpaired = (i == 12) || (u == t);
    const bool cfT = (t >= 288);
    const bool cfU = (u >= 288);
    const int c = lane;
    const int srcT = cfT ? 31 - c : c;
    const int srcU = cfU ? 31 - c : c;
    float fax = Fr[wv][0][srcT];
    float fay = Fi[wv][0][srcT];
    float fbx = Fr[wv][1][srcU];
    float fby = Fi[wv][1][srcU];
    float gr = fax;
    float gi = cfT ? -fay : fay;
    if(!unpaired){
      gr += fbx;
      gi -= (cfU ? -fby : fby);
    }
    unsigned short hr = f2b(gr); float lr = gr - b2f(hr);
    unsigned short hi2 = f2b(gi); float li = gi - b2f(hi2);
    int hhc = c >> 4, clc = c & 15;
    int kk1 = k >> 5, q1 = (k >> 3) & 3, e1 = k & 7;
    size_t fb2 = (size_t)(b * 2 + hhc) * 18;
    size_t off = (size_t)(q1 * 16 + clc) * 8 + e1;
    ghif[(fb2 + kk1) * 512 + off]     = hr;
    ghif[(fb2 + 9 + kk1) * 512 + off] = hi2;
    glof[(fb2 + kk1) * 512 + off]     = f2b(lr);
    glof[(fb2 + 9 + kk1) * 512 + off] = f2b(li);
  }
}

// ---------- inverse transform + MFMA-folded conv (+gelu | +MFMA fc1/fc2) — verbatim R9 ----------
template<int LAST>
__global__ __launch_bounds__(256, 6) void k_inv(const ushort_t* __restrict__ VTF,
    const ushort_t* __restrict__ ghif, const ushort_t* __restrict__ glof,
    const float* __restrict__ cbias, int layer,
    const ushort_t* __restrict__ hbCi_hi, const ushort_t* __restrict__ hbCi_lo,
    ushort_t* __restrict__ hbBo, ushort_t* __restrict__ hbCo_hi,
    ushort_t* __restrict__ hbCo_lo,
    const float* __restrict__ b1, const float* __restrict__ w2,
    const float* __restrict__ b2, float* __restrict__ out,
    const ushort_t* __restrict__ WBg, const ushort_t* __restrict__ WA)
{
  const int tid = threadIdx.x;
  const int b = blockIdx.y;
  const int bx = blockIdx.x;
  const int lane = tid & 63;
  const int w = tid >> 6;
  const int tl = w >> 1;
  const int hh = w & 1;
  const int row = lane & 15, q = lane >> 4;
  const int t16 = bx * 2 + tl;
  const ushort_t* vb = VTF + ((size_t)(b * 512 + t16) * 18) * 512 + lane * 8;
  const ushort_t* gh = ghif + ((size_t)(b * 2 + hh) * 18) * 512 + lane * 8;
  const ushort_t* gl = glof + ((size_t)(b * 2 + hh) * 18) * 512 + lane * 8;
  floatx4 ah = {0.f,0.f,0.f,0.f}, al = {0.f,0.f,0.f,0.f};
  #pragma unroll
  for(int kk = 0; kk < 18; ++kk){
    short8 Bv = *(const short8*)(vb + (size_t)kk * 512);
    short8 Ah = *(const short8*)(gh + (size_t)kk * 512);
    short8 Al = *(const short8*)(gl + (size_t)kk * 512);
    ah = __builtin_amdgcn_mfma_f32_16x16x32_bf16(Ah, Bv, ah, 0, 0, 0);
    al = __builtin_amdgcn_mfma_f32_16x16x32_bf16(Al, Bv, al, 0, 0, 0);
  }
  {
    short8 Whi = *(const short8*)(WA + ((size_t)((layer * 2 + 0) * 2 + hh)) * 512 + lane * 8);
    short8 Wlo = *(const short8*)(WA + ((size_t)((layer * 2 + 1) * 2 + hh)) * 512 + lane * 8);
    short8 Bhi = *(const short8*)(hbCi_hi + ((size_t)(b * 512 + t16)) * 512 + lane * 8);
    short8 Blo = *(const short8*)(hbCi_lo + ((size_t)(b * 512 + t16)) * 512 + lane * 8);
    ah = __builtin_amdgcn_mfma_f32_16x16x32_bf16(Whi, Bhi, ah, 0, 0, 0);
    al = __builtin_amdgcn_mfma_f32_16x16x32_bf16(Wlo, Bhi, al, 0, 0, 0);
    ah = __builtin_amdgcn_mfma_f32_16x16x32_bf16(Whi, Blo, ah, 0, 0, 0);
  }
  floatx4 accF = ah + al;
  const float sc = 2.0f / 8192.0f;
  float cb[4];
  #pragma unroll
  for(int r = 0; r < 4; ++r) cb[r] = cbias[layer * 32 + hh * 16 + q * 4 + r];
  if constexpr(!LAST){
    const int n = bx * 32 + tl * 16 + row;
    const int g2 = n >> 5, qb = (n >> 3) & 3, e2 = n & 7;
    #pragma unroll
    for(int r = 0; r < 4; ++r){
      int c = hh * 16 + q * 4 + r;
      float v = gelu_f(accF[r] * sc + cb[r]);
      ushort_t hi = f2b(v), lo = f2b(v - b2f(hi));
      hbBo[(((size_t)(b * 2 + hh) * 256 + g2) * 512) + (qb * 16 + (q * 4 + r)) * 8 + e2] = hi;
      size_t ca = ((size_t)(b * 512 + t16)) * 512 + ((c >> 3) * 16 + row) * 8 + (c & 7);
      hbCo_hi[ca] = hi; hbCo_lo[ca] = lo;
    }
  } else {
    __shared__ ushort_t hHi[32][36];
    __shared__ ushort_t hLo[32][36];
    __shared__ float part[2][32];
    {
      ushort_t H[4], L[4];
      #pragma unroll
      for(int r = 0; r < 4; ++r){
        float v = accF[r] * sc + cb[r];
        H[r] = f2b(v); L[r] = f2b(v - b2f(H[r]));
      }
      uint2 uu;
      uu.x = (unsigned)H[0] | ((unsigned)H[1] << 16);
      uu.y = (unsigned)H[2] | ((unsigned)H[3] << 16);
      *(uint2*)&hHi[tl * 16 + row][hh * 16 + q * 4] = uu;
      uu.x = (unsigned)L[0] | ((unsigned)L[1] << 16);
      uu.y = (unsigned)L[2] | ((unsigned)L[3] << 16);
      *(uint2*)&hLo[tl * 16 + row][hh * 16 + q * 4] = uu;
    }
    __syncthreads();
    const int cl = row;
    short8 Ahi = *(const short8*)&hHi[tl * 16 + cl][q * 8];
    short8 Alo = *(const short8*)&hLo[tl * 16 + cl][q * 8];
    float S0 = 0.f, S1 = 0.f, S2 = 0.f, S3 = 0.f;
    #pragma unroll
    for(int jt2 = 0; jt2 < 4; ++jt2){
      int jt = hh * 4 + jt2;
      short8 Bhi = *(const short8*)(WBg + (jt * 64 + lane) * 8);
      short8 Blo = *(const short8*)(WBg + 4096 + (jt * 64 + lane) * 8);
      floatx4 acc = {0.f, 0.f, 0.f, 0.f};
      acc = __builtin_amdgcn_mfma_f32_16x16x32_bf16(Ahi, Bhi, acc, 0, 0, 0);
      acc = __builtin_amdgcn_mfma_f32_16x16x32_bf16(Alo, Bhi, acc, 0, 0, 0);
      acc = __builtin_amdgcn_mfma_f32_16x16x32_bf16(Ahi, Blo, acc, 0, 0, 0);
      float bv = b1[jt * 16 + cl], wv = w2[jt * 16 + cl];
      S0 = fmaf(gelu_f(acc[0] + bv), wv, S0);
      S1 = fmaf(gelu_f(acc[1] + bv), wv, S1);
      S2 = fmaf(gelu_f(acc[2] + bv), wv, S2);
      S3 = fmaf(gelu_f(acc[3] + bv), wv, S3);
    }
    #pragma unroll
    for(int off = 8; off; off >>= 1){
      S0 += __shfl_xor(S0, off, 16);
      S1 += __shfl_xor(S1, off, 16);
      S2 += __shfl_xor(S2, off, 16);
      S3 += __shfl_xor(S3, off, 16);
    }
    if(cl == 0){
      int pb = tl * 16 + q * 4;
      part[hh][pb + 0] = S0;
      part[hh][pb + 1] = S1;
      part[hh][pb + 2] = S2;
      part[hh][pb + 3] = S3;
    }
    __syncthreads();
    if(tid < 32)
      out[(size_t)b * NN + bx * 32 + tid] = part[0][tid] + part[1][tid] + b2[0];
  }
}

// ---------- launch (10 dispatches: pre, vbuild, 4 x (fm + inv)) ----------
extern "C" void kernel_launch(void* const* d_in, const int* in_sizes, int n_in,
                              void* d_out, int out_size, void* d_ws, size_t ws_size,
                              hipStream_t stream)
{
  const float* x      = (const float*)d_in[0];
  const float* fc0_w  = (const float*)d_in[1];
  const float* fc0_b  = (const float*)d_in[2];
  const float* spec_w = (const float*)d_in[3];
  const float* conv_w = (const float*)d_in[4];
  const float* conv_b = (const float*)d_in[5];
  const float* fc1_w  = (const float*)d_in[6];
  const float* fc1_b  = (const float*)d_in[7];
  const float* fc2_w  = (const float*)d_in[8];
  const float* fc2_b  = (const float*)d_in[9];
  float* out = (float*)d_out;

  char* w = (char*)d_ws;
  const size_t OFF_PMM  = 0;
  const size_t OFF_WT   = 4096;
  const size_t OFF_AFR  = OFF_WT  + 9437184;
  const size_t OFF_VTF  = OFF_AFR + 75497472;   // AFR: 72 tiles (rep-grouped)
  const size_t OFF_HB0  = OFF_VTF + 37748736;
  const size_t OFF_HB1  = OFF_HB0 + 2097152;
  const size_t OFF_HC0  = OFF_HB1 + 2097152;
  const size_t OFF_HC1  = OFF_HC0 + 2097152;
  const size_t OFF_HL0  = OFF_HC1 + 2097152;
  const size_t OFF_HL1  = OFF_HL0 + 2097152;
  const size_t OFF_GHF  = OFF_HL1 + 2097152;
  const size_t OFF_GLO  = OFF_GHF + 147456;
  const size_t OFF_WB   = OFF_GLO + 147456;
  const size_t OFF_WA   = OFF_WB  + 16384;

  float4* pmm    = (float4*)(w + OFF_PMM);
  float2* wt     = (float2*)(w + OFF_WT);
  ushort_t* AFR  = (ushort_t*)(w + OFF_AFR);
  ushort_t* VTF  = (ushort_t*)(w + OFF_VTF);
  ushort_t* hbB[2]  = { (ushort_t*)(w + OFF_HB0), (ushort_t*)(w + OFF_HB1) };
  ushort_t* hbChi[2] = { (ushort_t*)(w + OFF_HC0), (ushort_t*)(w + OFF_HC1) };
  ushort_t* hbClo[2] = { (ushort_t*)(w + OFF_HL0), (ushort_t*)(w + OFF_HL1) };
  ushort_t* ghif = (ushort_t*)(w + OFF_GHF);
  ushort_t* glof = (ushort_t*)(w + OFF_GLO);
  ushort_t* WB   = (ushort_t*)(w + OFF_WB);
  ushort_t* WA   = (ushort_t*)(w + OFF_WA);

  hipLaunchKernelGGL(k_pre, dim3(4737), dim3(256), 0, stream, spec_w, wt, x, pmm,
                     fc1_w, WB, conv_w, WA);
  hipLaunchKernelGGL(k_vbuild, dim3(1024), dim3(256), 0, stream, x, pmm,
                     fc0_w, fc0_b, AFR, VTF, hbB[0], hbChi[0], hbClo[0]);

  for(int l = 0; l < 4; ++l){
    int in = l & 1, outb = 1 - in;
    hipLaunchKernelGGL(k_fm, dim3(72, NB), dim3(512), 0, stream, AFR, hbB[in], wt,
                       ghif, glof, l);
    if(l < 3)
      hipLaunchKernelGGL(k_inv<0>, dim3(256, NB), dim3(256), 0, stream, VTF, ghif, glof,
                         conv_b, l, hbChi[in], hbClo[in],
                         hbB[outb], hbChi[outb], hbClo[outb],
                         fc1_b, fc2_w, fc2_b, out, WB, WA);
    else
      hipLaunchKernelGGL(k_inv<1>, dim3(256, NB), dim3(256), 0, stream, VTF, ghif, glof,
                         conv_b, l, hbChi[in], hbClo[in],
                         hbB[outb], hbChi[outb], hbClo[outb],
                         fc1_b, fc2_w, fc2_b, out, WB, WA);
  }
  (void)in_sizes; (void)n_in; (void)out_size; (void)ws_size;
}